// Round 1
// baseline (907.146 us; speedup 1.0000x reference)
//
#include <hip/hip_runtime.h>
#include <cstdint>

// ---------------------------------------------------------------------------
// BinaryNet forward.  Key identities:
//  * binary_tanh(bn2d(conv+b)) == (alpha*conv + beta >= 0 ? +1 : -1), biases cancel.
//  * binary conv of +-1 values == exact integers via XNOR-popcount.
//  * head is exact in f32; bn1d stats in f64.
//  * conv1 decisions recomputed in f64 (flip-proof vs f64 reference).
// ---------------------------------------------------------------------------

__global__ void pack_w_kern(const float* __restrict__ w, uint32_t* __restrict__ wp,
                            int Co, int Ci) {
  const int W = Ci >> 5;
  const int total = Co * 9 * W;
  const int idx = blockIdx.x * 256 + threadIdx.x;
  if (idx >= total) return;
  const int wd = idx % W;
  const int t = idx / W;
  const int k = t % 9;       // ky*3+kx
  const int co = t / 9;
  uint32_t bits = 0u;
  for (int j = 0; j < 32; j++) {
    const float v = w[(size_t)(co * Ci + (wd * 32 + j)) * 9 + k];
    bits |= (v >= 0.f ? 1u : 0u) << j;   // bit 1 <=> +1
  }
  wp[idx] = bits;
}

// ---- conv1 pass 1: f32 conv, per-(image,channel) double partial stats ----
__global__ void __launch_bounds__(256) conv1_p1(const float* __restrict__ x,
                                                const float* __restrict__ w1,
                                                double2* __restrict__ part) {
  __shared__ float ximg[3][34][34];
  __shared__ float wl[64][28];
  __shared__ double pS[64][4], pQ[64][4];
  const int tid = threadIdx.x, n = blockIdx.x;
  for (int i = tid; i < 3 * 34 * 34; i += 256) ((float*)ximg)[i] = 0.f;
  for (int i = tid; i < 1728; i += 256) wl[i / 27][i % 27] = w1[i];
  __syncthreads();
  const float* xb = x + (size_t)n * 3072;
  for (int i = tid; i < 3072; i += 256) {
    const int c = i >> 10, p = i & 1023;
    ximg[c][(p >> 5) + 1][(p & 31) + 1] = xb[i];
  }
  __syncthreads();
  const int h = tid >> 3, w0 = (tid & 7) * 4;
  const int lane = tid & 63, wv = tid >> 6;
  for (int co = 0; co < 64; co++) {
    float acc[4] = {0.f, 0.f, 0.f, 0.f};
#pragma unroll
    for (int ic = 0; ic < 3; ic++)
#pragma unroll
      for (int ky = 0; ky < 3; ky++) {
        float xr[6];
#pragma unroll
        for (int t = 0; t < 6; t++) xr[t] = ximg[ic][h + ky][w0 + t];
#pragma unroll
        for (int kx = 0; kx < 3; kx++) {
          const float wgt = wl[co][ic * 9 + ky * 3 + kx];
#pragma unroll
          for (int j = 0; j < 4; j++) acc[j] = fmaf(xr[j + kx], wgt, acc[j]);
        }
      }
    double s = (double)acc[0] + acc[1] + acc[2] + acc[3];
    double q = (double)acc[0] * acc[0] + (double)acc[1] * acc[1] +
               (double)acc[2] * acc[2] + (double)acc[3] * acc[3];
#pragma unroll
    for (int off = 32; off; off >>= 1) {
      s += __shfl_down(s, off);
      q += __shfl_down(q, off);
    }
    if (lane == 0) { pS[co][wv] = s; pQ[co][wv] = q; }
  }
  __syncthreads();
  if (tid < 64) {
    const double S = pS[tid][0] + pS[tid][1] + pS[tid][2] + pS[tid][3];
    const double Q = pQ[tid][0] + pQ[tid][1] + pQ[tid][2] + pQ[tid][3];
    part[tid * 512 + n] = make_double2(S, Q);
  }
}

__global__ void conv1_fin(const double2* __restrict__ part, const float* __restrict__ g,
                          const float* __restrict__ be, double2* __restrict__ thr) {
  const int c = threadIdx.x;  // 64
  double S = 0.0, Q = 0.0;
  for (int n = 0; n < 512; n++) { const double2 v = part[c * 512 + n]; S += v.x; Q += v.y; }
  const double Nel = 512.0 * 1024.0;
  const double mu = S / Nel, var = Q / Nel - mu * mu;
  const double r = 1.0 / sqrt(var + 1e-4);
  const double al = (double)g[c] * r;
  const double bt = (double)be[c] - al * mu;
  thr[c] = make_double2(al, bt);
}

// ---- conv1 pass 2: f64 recompute + binarize + bit-pack (layout [n][p][2]) ----
__global__ void __launch_bounds__(256) conv1_p2(const float* __restrict__ x,
                                                const float* __restrict__ w1,
                                                const double2* __restrict__ thr,
                                                uint32_t* __restrict__ A1) {
  __shared__ float ximg[3][34][34];
  __shared__ float wl[64][28];
  __shared__ double2 tl[64];
  const int tid = threadIdx.x, n = blockIdx.x;
  for (int i = tid; i < 3 * 34 * 34; i += 256) ((float*)ximg)[i] = 0.f;
  for (int i = tid; i < 1728; i += 256) wl[i / 27][i % 27] = w1[i];
  for (int i = tid; i < 64; i += 256) tl[i] = thr[i];
  __syncthreads();
  const float* xb = x + (size_t)n * 3072;
  for (int i = tid; i < 3072; i += 256) {
    const int c = i >> 10, p = i & 1023;
    ximg[c][(p >> 5) + 1][(p & 31) + 1] = xb[i];
  }
  __syncthreads();
  const int h = tid >> 3, w0 = (tid & 7) * 4;
  uint32_t wbits[4][2] = {{0u, 0u}, {0u, 0u}, {0u, 0u}, {0u, 0u}};
  for (int co = 0; co < 64; co++) {
    double acc[4] = {0.0, 0.0, 0.0, 0.0};
#pragma unroll
    for (int ic = 0; ic < 3; ic++)
#pragma unroll
      for (int ky = 0; ky < 3; ky++) {
        double xd[6];
#pragma unroll
        for (int t = 0; t < 6; t++) xd[t] = (double)ximg[ic][h + ky][w0 + t];
#pragma unroll
        for (int kx = 0; kx < 3; kx++) {
          const double wgt = (double)wl[co][ic * 9 + ky * 3 + kx];
#pragma unroll
          for (int j = 0; j < 4; j++) acc[j] = fma(xd[j + kx], wgt, acc[j]);
        }
      }
    const double2 ab = tl[co];
    const int wd = co >> 5, sh = co & 31;
#pragma unroll
    for (int j = 0; j < 4; j++)
      if (fma(ab.x, acc[j], ab.y) >= 0.0) wbits[j][wd] |= (1u << sh);
  }
#pragma unroll
  for (int j = 0; j < 4; j++) {
    const int p = h * 32 + w0 + j;
#pragma unroll
    for (int wd = 0; wd < 2; wd++) A1[((size_t)n * 1024 + p) * 2 + wd] = wbits[j][wd];
  }
}

// ---- binary conv: XNOR-popcount, exact int, integer-atomic stats ----
template <int H, int W, int WD, int CO, int CC>
__global__ void __launch_bounds__(256) bconv_kern(const uint32_t* __restrict__ Ain,
                                                  const uint32_t* __restrict__ Wp,
                                                  short* __restrict__ raw,
                                                  unsigned long long* __restrict__ stats) {
  constexpr int P = H * W;
  constexpr int IMG = P * WD;
  constexpr int GP = (P >= 256) ? 256 : P;  // pixels per co-group (== wave when 64)
  constexpr int NG = 256 / GP;
  constexpr int PT = P / GP;
  __shared__ uint32_t img[IMG];
  __shared__ uint32_t wl[CC * 9 * WD];
  __shared__ int partS[CC][4], partQ[CC][4];
  const int tid = threadIdx.x;
  const int n = blockIdx.x;
  const int cg = blockIdx.y;
  const uint32_t* src = Ain + (size_t)n * IMG;
  for (int i = tid; i < IMG; i += 256) img[i] = src[i];
  const uint32_t* wsrc = Wp + (size_t)(cg * CC) * 9 * WD;
  for (int i = tid; i < CC * 9 * WD; i += 256) wl[i] = wsrc[i];
  __syncthreads();
  const int group = tid / GP;
  const int pid = tid % GP;
  const int lane = tid & 63, wv = tid >> 6;
  for (int cb = 0; cb < CC; cb += NG) {
    const int col = cb + group;
    const int co = cg * CC + col;
    int s = 0, q = 0;
#pragma unroll
    for (int i = 0; i < PT; i++) {
      const int p = pid + i * GP;
      const int h = p / W, w = p % W;
      int acc = 0, vt = 0;
#pragma unroll
      for (int ky = 0; ky < 3; ky++) {
        const int hy = h + ky - 1;
        if ((unsigned)hy >= (unsigned)H) continue;
#pragma unroll
        for (int kx = 0; kx < 3; kx++) {
          const int wx = w + kx - 1;
          if ((unsigned)wx >= (unsigned)W) continue;
          vt++;
          const uint32_t* ap = &img[(hy * W + wx) * WD];
          const uint32_t* wp2 = &wl[(col * 9 + ky * 3 + kx) * WD];
#pragma unroll
          for (int d = 0; d < WD; d++) acc += __popc(ap[d] ^ wp2[d]);
        }
      }
      const int val = 32 * WD * vt - 2 * acc;  // exact +-1 dot product
      raw[(size_t)co * ((size_t)512 * P) + (size_t)n * P + p] = (short)val;
      s += val;
      q += val * val;
    }
#pragma unroll
    for (int off = 32; off; off >>= 1) {
      s += __shfl_down(s, off);
      q += __shfl_down(q, off);
    }
    if (GP == 64) {
      if (lane == 0) {
        atomicAdd(&stats[2 * co], (unsigned long long)(long long)s);
        atomicAdd(&stats[2 * co + 1], (unsigned long long)(long long)q);
      }
    } else {
      if (lane == 0) { partS[col][wv] = s; partQ[col][wv] = q; }
    }
  }
  if (GP == 256) {
    __syncthreads();
    for (int c = tid; c < CC; c += 256) {
      const long long S = (long long)partS[c][0] + partS[c][1] + partS[c][2] + partS[c][3];
      const long long Q = (long long)partQ[c][0] + partQ[c][1] + partQ[c][2] + partQ[c][3];
      const int co = cg * CC + c;
      atomicAdd(&stats[2 * co], (unsigned long long)S);
      atomicAdd(&stats[2 * co + 1], (unsigned long long)Q);
    }
  }
}

__global__ void bin_fin(const unsigned long long* __restrict__ stats,
                        const float* __restrict__ g, const float* __restrict__ be,
                        double2* __restrict__ thr, int Co, double Nel) {
  const int c = blockIdx.x * 64 + threadIdx.x;
  if (c >= Co) return;
  const double S = (double)(long long)stats[2 * c];
  const double Q = (double)(long long)stats[2 * c + 1];
  const double mu = S / Nel, var = Q / Nel - mu * mu;
  const double r = 1.0 / sqrt(var + 1e-4);
  const double al = (double)g[c] * r;
  const double bt = (double)be[c] - al * mu;
  thr[c] = make_double2(al, bt);
}

// ---- binarize (no pool): raw [co][n*P] -> packed A [n*P][CO/32] ----
template <int P, int CO>
__global__ void __launch_bounds__(256) binz_kern(const short* __restrict__ raw,
                                                 const double2* __restrict__ thr,
                                                 uint32_t* __restrict__ Aout) {
  constexpr int WDo = CO / 32;
  const int idx = blockIdx.x * 256 + threadIdx.x;
  if (idx >= 512 * P * WDo) return;
  const int np = idx % (512 * P);   // wave-contiguous -> coalesced raw reads
  const int wd = idx / (512 * P);   // wave-uniform -> broadcast thr loads
  uint32_t word = 0;
#pragma unroll
  for (int j = 0; j < 32; j++) {
    const int co = wd * 32 + j;
    const int v = raw[(size_t)co * ((size_t)512 * P) + np];
    const double2 ab = thr[co];
    if (fma(ab.x, (double)v, ab.y) >= 0.0) word |= (1u << j);
  }
  Aout[(size_t)np * WDo + wd] = word;
}

// ---- binarize + 2x2 maxpool (OR of decisions) ----
template <int Hs, int CO>
__global__ void __launch_bounds__(256) binpool_kern(const short* __restrict__ raw,
                                                    const double2* __restrict__ thr,
                                                    uint32_t* __restrict__ Aout) {
  constexpr int Ws = Hs, Ps = Hs * Hs, Ho = Hs / 2, Po = Ho * Ho;
  constexpr int WDo = CO / 32;
  const int idx = blockIdx.x * 256 + threadIdx.x;
  if (idx >= 512 * Po * WDo) return;
  const int npo = idx % (512 * Po);
  const int wd = idx / (512 * Po);
  const int n = npo / Po, po = npo % Po;
  const int ho = po / Ho, wo = po % Ho;
  const int p00 = (2 * ho) * Ws + 2 * wo;
  uint32_t word = 0;
#pragma unroll
  for (int j = 0; j < 32; j++) {
    const int co = wd * 32 + j;
    const size_t base = (size_t)co * ((size_t)512 * Ps) + (size_t)n * Ps;
    const double2 ab = thr[co];
    bool b = false;
    b |= fma(ab.x, (double)raw[base + p00], ab.y) >= 0.0;
    b |= fma(ab.x, (double)raw[base + p00 + 1], ab.y) >= 0.0;
    b |= fma(ab.x, (double)raw[base + p00 + Ws], ab.y) >= 0.0;
    b |= fma(ab.x, (double)raw[base + p00 + Ws + 1], ab.y) >= 0.0;
    if (b) word |= (1u << j);
  }
  Aout[(size_t)npo * WDo + wd] = word;
}

// ---- head: avgpool(4x4) + binary FC (exact in f32) ----
__global__ void __launch_bounds__(64) head_kern(const uint32_t* __restrict__ A6,
                                                const float* __restrict__ fcw,
                                                const float* __restrict__ fcb,
                                                float* __restrict__ fcout) {
  __shared__ uint32_t aw[128];
  __shared__ float feat[256];
  const int n = blockIdx.x, t = threadIdx.x;
  for (int i = t; i < 128; i += 64) aw[i] = A6[(size_t)n * 128 + i];
  __syncthreads();
#pragma unroll
  for (int k = 0; k < 4; k++) {
    const int c = t * 4 + k;
    const int wd = c >> 5, sh = c & 31;
    int cnt = 0;
#pragma unroll
    for (int pos = 0; pos < 16; pos++) cnt += (aw[pos * 8 + wd] >> sh) & 1;
    feat[c] = (float)(cnt - 8) * 0.125f;  // exact
  }
  __syncthreads();
  if (t < 10) {
    float acc = 0.f;  // all partial sums exactly representable
    for (int c = 0; c < 256; c++) acc += (fcw[t * 256 + c] >= 0.f ? feat[c] : -feat[c]);
    fcout[n * 10 + t] = acc + fcb[t];
  }
}

// ---- bn1d over batch: one block, wave per output channel ----
__global__ void __launch_bounds__(640) bn1d_kern(const float* __restrict__ fcout,
                                                 const float* __restrict__ g7,
                                                 const float* __restrict__ be7,
                                                 float* __restrict__ out) {
  const int t = threadIdx.x, o = t >> 6, lane = t & 63;
  double s = 0.0, q = 0.0;
  float v[8];
#pragma unroll
  for (int i = 0; i < 8; i++) {
    v[i] = fcout[(lane + 64 * i) * 10 + o];
    s += v[i];
    q += (double)v[i] * v[i];
  }
#pragma unroll
  for (int off = 32; off; off >>= 1) {
    s += __shfl_down(s, off);
    q += __shfl_down(q, off);
  }
  s = __shfl(s, 0);
  q = __shfl(q, 0);
  const double mu = s / 512.0, var = q / 512.0 - mu * mu;
  const double r = 1.0 / sqrt(var + 1e-5);
  const double al = (double)g7[o] * r;
  const double bt = (double)be7[o] - al * mu;
#pragma unroll
  for (int i = 0; i < 8; i++) out[(lane + 64 * i) * 10 + o] = (float)fma(al, (double)v[i], bt);
}

extern "C" void kernel_launch(void* const* d_in, const int* in_sizes, int n_in,
                              void* d_out, int out_size, void* d_ws, size_t ws_size,
                              hipStream_t stream) {
  const float* x = (const float*)d_in[0];
  const float* w1 = (const float*)d_in[1];
  const float* g1 = (const float*)d_in[3];
  const float* be1 = (const float*)d_in[4];
  const float* w2 = (const float*)d_in[5];
  const float* g2 = (const float*)d_in[7];
  const float* be2 = (const float*)d_in[8];
  const float* w3 = (const float*)d_in[9];
  const float* g3 = (const float*)d_in[11];
  const float* be3 = (const float*)d_in[12];
  const float* w4 = (const float*)d_in[13];
  const float* g4 = (const float*)d_in[15];
  const float* be4 = (const float*)d_in[16];
  const float* w5 = (const float*)d_in[17];
  const float* g5 = (const float*)d_in[19];
  const float* be5 = (const float*)d_in[20];
  const float* w6 = (const float*)d_in[21];
  const float* g6 = (const float*)d_in[23];
  const float* be6 = (const float*)d_in[24];
  const float* fcw = (const float*)d_in[25];
  const float* fcb = (const float*)d_in[26];
  const float* g7 = (const float*)d_in[27];
  const float* be7 = (const float*)d_in[28];
  float* out = (float*)d_out;

  char* ws = (char*)d_ws;
  size_t off = 0;
  auto take = [&](size_t bytes) -> char* {
    char* p = ws + off;
    off = (off + bytes + 255) & ~(size_t)255;
    return p;
  };
  uint32_t* A1 = (uint32_t*)take((size_t)512 * 1024 * 2 * 4);
  uint32_t* A2 = (uint32_t*)take((size_t)512 * 256 * 2 * 4);
  uint32_t* A3 = (uint32_t*)take((size_t)512 * 256 * 4 * 4);
  uint32_t* A4 = (uint32_t*)take((size_t)512 * 64 * 4 * 4);
  uint32_t* A5 = (uint32_t*)take((size_t)512 * 64 * 8 * 4);
  uint32_t* A6 = (uint32_t*)take((size_t)512 * 16 * 8 * 4);
  uint32_t* Wp2 = (uint32_t*)take((size_t)64 * 9 * 2 * 4);
  uint32_t* Wp3 = (uint32_t*)take((size_t)128 * 9 * 2 * 4);
  uint32_t* Wp4 = (uint32_t*)take((size_t)128 * 9 * 4 * 4);
  uint32_t* Wp5 = (uint32_t*)take((size_t)256 * 9 * 4 * 4);
  uint32_t* Wp6 = (uint32_t*)take((size_t)256 * 9 * 8 * 4);
  double2* part1 = (double2*)take((size_t)64 * 512 * 16);
  unsigned long long* stats = (unsigned long long*)take((size_t)832 * 2 * 8);
  double2* thr = (double2*)take((size_t)896 * 16);
  float* fcout = (float*)take((size_t)512 * 10 * 4);
  short* raw = (short*)take((size_t)64 * 512 * 1024 * 2);
  (void)ws_size; (void)in_sizes; (void)n_in; (void)out_size;

  hipMemsetAsync(stats, 0, 832 * 2 * 8, stream);

  pack_w_kern<<<(64 * 9 * 2 + 255) / 256, 256, 0, stream>>>(w2, Wp2, 64, 64);
  pack_w_kern<<<(128 * 9 * 2 + 255) / 256, 256, 0, stream>>>(w3, Wp3, 128, 64);
  pack_w_kern<<<(128 * 9 * 4 + 255) / 256, 256, 0, stream>>>(w4, Wp4, 128, 128);
  pack_w_kern<<<(256 * 9 * 4 + 255) / 256, 256, 0, stream>>>(w5, Wp5, 256, 128);
  pack_w_kern<<<(256 * 9 * 8 + 255) / 256, 256, 0, stream>>>(w6, Wp6, 256, 256);

  conv1_p1<<<512, 256, 0, stream>>>(x, w1, part1);
  conv1_fin<<<1, 64, 0, stream>>>(part1, g1, be1, thr);
  conv1_p2<<<512, 256, 0, stream>>>(x, w1, thr, A1);

  bconv_kern<32, 32, 2, 64, 16><<<dim3(512, 4), 256, 0, stream>>>(A1, Wp2, raw, stats + 0);
  bin_fin<<<1, 64, 0, stream>>>(stats + 0, g2, be2, thr + 64, 64, 512.0 * 1024.0);
  binpool_kern<32, 64><<<512 * 256 * 2 / 256, 256, 0, stream>>>(raw, thr + 64, A2);

  bconv_kern<16, 16, 2, 128, 16><<<dim3(512, 8), 256, 0, stream>>>(A2, Wp3, raw, stats + 128);
  bin_fin<<<2, 64, 0, stream>>>(stats + 128, g3, be3, thr + 128, 128, 512.0 * 256.0);
  binz_kern<256, 128><<<512 * 256 * 4 / 256, 256, 0, stream>>>(raw, thr + 128, A3);

  bconv_kern<16, 16, 4, 128, 16><<<dim3(512, 8), 256, 0, stream>>>(A3, Wp4, raw, stats + 384);
  bin_fin<<<2, 64, 0, stream>>>(stats + 384, g4, be4, thr + 256, 128, 512.0 * 256.0);
  binpool_kern<16, 128><<<512 * 64 * 4 / 256, 256, 0, stream>>>(raw, thr + 256, A4);

  bconv_kern<8, 8, 4, 256, 32><<<dim3(512, 8), 256, 0, stream>>>(A4, Wp5, raw, stats + 640);
  bin_fin<<<4, 64, 0, stream>>>(stats + 640, g5, be5, thr + 384, 256, 512.0 * 64.0);
  binz_kern<64, 256><<<512 * 64 * 8 / 256, 256, 0, stream>>>(raw, thr + 384, A5);

  bconv_kern<8, 8, 8, 256, 32><<<dim3(512, 8), 256, 0, stream>>>(A5, Wp6, raw, stats + 1152);
  bin_fin<<<4, 64, 0, stream>>>(stats + 1152, g6, be6, thr + 640, 256, 512.0 * 64.0);
  binpool_kern<8, 256><<<512 * 16 * 8 / 256, 256, 0, stream>>>(raw, thr + 640, A6);

  head_kern<<<512, 64, 0, stream>>>(A6, fcw, fcb, fcout);
  bn1d_kern<<<1, 640, 0, stream>>>(fcout, g7, be7, out);
}

// Round 2
// 643.464 us; speedup vs baseline: 1.4098x; 1.4098x over previous
//
#include <hip/hip_runtime.h>
#include <cstdint>

// ---------------------------------------------------------------------------
// BinaryNet forward.  Key identities:
//  * binary_tanh(bn2d(conv+b)) == (alpha*conv + beta >= 0 ? +1 : -1), biases cancel.
//  * binary conv of +-1 values == exact integers via XNOR-popcount.
//  * integer thresholds T (verified with f64 fma at T and T+-1) make the
//    binarize decision bit-identical to the f64 fma compare.
//  * conv1 decisions recomputed in f64 (flip-proof vs f64 reference).
// ---------------------------------------------------------------------------

// ---- merged weight pack: bits + per-tap popcount, record stride R ----------
// record layout per co: [k*WD+d] 9*WD words, then pw[k] 9 words, padded to R.
__global__ void __launch_bounds__(64) pack_all(const float* __restrict__ w2,
                                               const float* __restrict__ w3,
                                               const float* __restrict__ w4,
                                               const float* __restrict__ w5,
                                               const float* __restrict__ w6,
                                               uint32_t* __restrict__ Wr) {
  const int bid = blockIdx.x;
  const float* w; int Ci, base, l;
  if (bid < 64)        { w = w2; Ci = 64;  base = 0;     l = bid; }
  else if (bid < 192)  { w = w3; Ci = 64;  base = 1792;  l = bid - 64; }
  else if (bid < 320)  { w = w4; Ci = 128; base = 5376;  l = bid - 192; }
  else if (bid < 576)  { w = w5; Ci = 128; base = 11520; l = bid - 320; }
  else                 { w = w6; Ci = 256; base = 23808; l = bid - 576; }
  const int WD = Ci >> 5;
  const int R = (9 * WD + 9 + 3) & ~3;
  __shared__ uint32_t wloc[72];
  const int t = threadIdx.x;
  for (int i = t; i < 9 * WD; i += 64) {
    const int k = i / WD, d = i % WD;
    uint32_t bits = 0u;
    for (int j = 0; j < 32; j++)
      bits |= (w[((size_t)l * Ci + d * 32 + j) * 9 + k] >= 0.f ? 1u : 0u) << j;
    wloc[i] = bits;
    Wr[base + (size_t)l * R + i] = bits;
  }
  __syncthreads();
  if (t < 9) {
    int pw = 0;
    for (int d = 0; d < WD; d++) pw += __popc(wloc[t * WD + d]);
    Wr[base + (size_t)l * R + 9 * WD + t] = (uint32_t)pw;
  }
}

// ---- conv1 pass 1: f32 conv, per-(image,channel) double partial stats ----
__global__ void __launch_bounds__(256) conv1_p1(const float* __restrict__ x,
                                                const float* __restrict__ w1,
                                                double2* __restrict__ part) {
  __shared__ float ximg[3][34][34];
  __shared__ float wl[64][28];
  __shared__ double pS[64][4], pQ[64][4];
  const int tid = threadIdx.x, n = blockIdx.x;
  for (int i = tid; i < 3 * 34 * 34; i += 256) ((float*)ximg)[i] = 0.f;
  for (int i = tid; i < 1728; i += 256) wl[i / 27][i % 27] = w1[i];
  __syncthreads();
  const float* xb = x + (size_t)n * 3072;
  for (int i = tid; i < 3072; i += 256) {
    const int c = i >> 10, p = i & 1023;
    ximg[c][(p >> 5) + 1][(p & 31) + 1] = xb[i];
  }
  __syncthreads();
  const int h = tid >> 3, w0 = (tid & 7) * 4;
  const int lane = tid & 63, wv = tid >> 6;
  for (int co = 0; co < 64; co++) {
    float acc[4] = {0.f, 0.f, 0.f, 0.f};
#pragma unroll
    for (int ic = 0; ic < 3; ic++)
#pragma unroll
      for (int ky = 0; ky < 3; ky++) {
        float xr[6];
#pragma unroll
        for (int t = 0; t < 6; t++) xr[t] = ximg[ic][h + ky][w0 + t];
#pragma unroll
        for (int kx = 0; kx < 3; kx++) {
          const float wgt = wl[co][ic * 9 + ky * 3 + kx];
#pragma unroll
          for (int j = 0; j < 4; j++) acc[j] = fmaf(xr[j + kx], wgt, acc[j]);
        }
      }
    double s = (double)acc[0] + acc[1] + acc[2] + acc[3];
    double q = (double)acc[0] * acc[0] + (double)acc[1] * acc[1] +
               (double)acc[2] * acc[2] + (double)acc[3] * acc[3];
#pragma unroll
    for (int off = 32; off; off >>= 1) {
      s += __shfl_down(s, off);
      q += __shfl_down(q, off);
    }
    if (lane == 0) { pS[co][wv] = s; pQ[co][wv] = q; }
  }
  __syncthreads();
  if (tid < 64) {
    const double S = pS[tid][0] + pS[tid][1] + pS[tid][2] + pS[tid][3];
    const double Q = pQ[tid][0] + pQ[tid][1] + pQ[tid][2] + pQ[tid][3];
    part[tid * 512 + n] = make_double2(S, Q);
  }
}

__global__ void conv1_fin(const double2* __restrict__ part, const float* __restrict__ g,
                          const float* __restrict__ be, double2* __restrict__ thr) {
  const int c = threadIdx.x;  // 64
  double S = 0.0, Q = 0.0;
  for (int n = 0; n < 512; n++) { const double2 v = part[c * 512 + n]; S += v.x; Q += v.y; }
  const double Nel = 512.0 * 1024.0;
  const double mu = S / Nel, var = Q / Nel - mu * mu;
  const double r = 1.0 / sqrt(var + 1e-4);
  const double al = (double)g[c] * r;
  const double bt = (double)be[c] - al * mu;
  thr[c] = make_double2(al, bt);
}

// ---- conv1 pass 2: f64 recompute + binarize + bit-pack (layout [n][p][2]) ----
__global__ void __launch_bounds__(256) conv1_p2(const float* __restrict__ x,
                                                const float* __restrict__ w1,
                                                const double2* __restrict__ thr,
                                                uint32_t* __restrict__ A1) {
  __shared__ float ximg[3][34][34];
  __shared__ float wl[64][28];
  __shared__ double2 tl[64];
  const int tid = threadIdx.x, n = blockIdx.x;
  for (int i = tid; i < 3 * 34 * 34; i += 256) ((float*)ximg)[i] = 0.f;
  for (int i = tid; i < 1728; i += 256) wl[i / 27][i % 27] = w1[i];
  for (int i = tid; i < 64; i += 256) tl[i] = thr[i];
  __syncthreads();
  const float* xb = x + (size_t)n * 3072;
  for (int i = tid; i < 3072; i += 256) {
    const int c = i >> 10, p = i & 1023;
    ximg[c][(p >> 5) + 1][(p & 31) + 1] = xb[i];
  }
  __syncthreads();
  const int h = tid >> 3, w0 = (tid & 7) * 4;
  uint32_t wbits[4][2] = {{0u, 0u}, {0u, 0u}, {0u, 0u}, {0u, 0u}};
  for (int co = 0; co < 64; co++) {
    double acc[4] = {0.0, 0.0, 0.0, 0.0};
#pragma unroll
    for (int ic = 0; ic < 3; ic++)
#pragma unroll
      for (int ky = 0; ky < 3; ky++) {
        double xd[6];
#pragma unroll
        for (int t = 0; t < 6; t++) xd[t] = (double)ximg[ic][h + ky][w0 + t];
#pragma unroll
        for (int kx = 0; kx < 3; kx++) {
          const double wgt = (double)wl[co][ic * 9 + ky * 3 + kx];
#pragma unroll
          for (int j = 0; j < 4; j++) acc[j] = fma(xd[j + kx], wgt, acc[j]);
        }
      }
    const double2 ab = tl[co];
    const int wd = co >> 5, sh = co & 31;
#pragma unroll
    for (int j = 0; j < 4; j++)
      if (fma(ab.x, acc[j], ab.y) >= 0.0) wbits[j][wd] |= (1u << sh);
  }
#pragma unroll
  for (int j = 0; j < 4; j++) {
    const int p = h * 32 + w0 + j;
#pragma unroll
    for (int wd = 0; wd < 2; wd++) A1[((size_t)n * 1024 + p) * 2 + wd] = wbits[j][wd];
  }
}

// ---- vector LDS load helper ----
template <int WD>
__device__ __forceinline__ void ldvec(const uint32_t* p, uint32_t* dst) {
  if constexpr (WD == 2) {
    const uint2 v = *(const uint2*)p;
    dst[0] = v.x; dst[1] = v.y;
  } else if constexpr (WD == 4) {
    const uint4 v = *(const uint4*)p;
    dst[0] = v.x; dst[1] = v.y; dst[2] = v.z; dst[3] = v.w;
  } else {
    const uint4 a = *(const uint4*)p, b = *(const uint4*)(p + 4);
    dst[0] = a.x; dst[1] = a.y; dst[2] = a.z; dst[3] = a.w;
    dst[4] = b.x; dst[5] = b.y; dst[6] = b.z; dst[7] = b.w;
  }
}

// ---- binary conv v2: window-in-registers, channel-inner, padded LDS --------
// block = 256 threads, handles IPB images x CS output channels.
template <int H, int W, int WD, int CO, int CS, int PT, int IPB>
__global__ void __launch_bounds__(256) bconv2(const uint32_t* __restrict__ Ain,
                                              const uint32_t* __restrict__ Wrec,
                                              short* __restrict__ raw,
                                              unsigned long long* __restrict__ stats) {
  constexpr int P = H * W;
  constexpr int Wp2 = W + 2;
  constexpr int IMGW = (H + 2) * Wp2 * WD;           // padded words per image
  constexpr int R = (9 * WD + 9 + 3) & ~3;           // record stride (words)
  constexpr int CPG = W / PT;                        // col groups per row
  constexpr int TPI = H * CPG;                       // threads per image
  static_assert(TPI * IPB == 256, "bad geometry");
  __shared__ __align__(16) uint32_t img[IPB * IMGW];
  __shared__ __align__(16) uint32_t wl[CS * R];
  __shared__ int partS[CS][16], partQ[CS][16];

  const int tid = threadIdx.x;
  const int n0 = blockIdx.x * IPB;
  const int cg = blockIdx.y;

  for (int i = tid; i < IPB * IMGW; i += 256) img[i] = 0u;
  const uint32_t* wsrc = Wrec + (size_t)cg * CS * R;
  for (int i = tid; i < CS * R; i += 256) wl[i] = wsrc[i];
  __syncthreads();
  const uint32_t* src = Ain + (size_t)n0 * P * WD;
  for (int i = tid; i < IPB * P * WD; i += 256) {
    const int d = i & (WD - 1);
    const int pp = i / WD;
    const int p = pp & (P - 1);
    const int im = pp / P;
    const int h = p / W, w = p % W;
    img[im * IMGW + ((h + 1) * Wp2 + (w + 1)) * WD + d] = src[i];
  }
  __syncthreads();

  const int iid = tid / TPI;
  const int r = tid % TPI;
  const int h = r / CPG;
  const int w0 = (r % CPG) * PT;
  const int n = n0 + iid;

  // load 3x(PT+2)xWD window into registers (once)
  uint32_t win[3][(PT + 2) * WD];
  const uint32_t* imgp = img + iid * IMGW;
#pragma unroll
  for (int ky = 0; ky < 3; ky++) {
    const uint32_t* rp = imgp + ((h + ky) * Wp2 + w0) * WD;
#pragma unroll
    for (int cc = 0; cc < PT + 2; cc++) ldvec<WD>(rp + cc * WD, &win[ky][cc * WD]);
  }

  // invalid-tap masks per pixel
  const int rowm = (h == 0 ? 1 : 0) | (h == H - 1 ? 4 : 0);
  unsigned masks[PT];
#pragma unroll
  for (int j = 0; j < PT; j++) {
    const int w = w0 + j;
    const int colm = (w == 0 ? 1 : 0) | (w == W - 1 ? 4 : 0);
    unsigned m = 0;
#pragma unroll
    for (int ky = 0; ky < 3; ky++)
#pragma unroll
      for (int kx = 0; kx < 3; kx++)
        if ((((rowm >> ky) | (colm >> kx)) & 1) != 0) m |= 1u << (ky * 3 + kx);
    masks[j] = m;
  }

  const int p0 = h * W + w0;
#pragma unroll 2
  for (int c = 0; c < CS; ++c) {
    const uint32_t* rec = wl + c * R;
    int acc[PT];
#pragma unroll
    for (int j = 0; j < PT; j++) acc[j] = 0;
#pragma unroll
    for (int ky = 0; ky < 3; ky++)
#pragma unroll
      for (int kx = 0; kx < 3; kx++) {
        uint32_t wt[WD];
        ldvec<WD>(rec + (ky * 3 + kx) * WD, wt);
#pragma unroll
        for (int j = 0; j < PT; j++)
#pragma unroll
          for (int d = 0; d < WD; d++)
            acc[j] += __popc(win[ky][(j + kx) * WD + d] ^ wt[d]);
      }
    int s = 0, q = 0;
    short vals[PT];
#pragma unroll
    for (int j = 0; j < PT; j++) {
      int val = 32 * WD * 9 - 2 * acc[j];
      unsigned m = masks[j];
      while (m) {
        const int k = __builtin_ctz(m);
        m &= m - 1;
        val += 2 * (int)rec[9 * WD + k] - 32 * WD;
      }
      vals[j] = (short)val;
      s += val;
      q += val * val;
    }
    const size_t co = (size_t)(cg * CS + c);
    short* dst = raw + co * ((size_t)512 * P) + (size_t)n * P + p0;
    if constexpr (PT == 4) {
      *(short4*)dst = make_short4(vals[0], vals[1], vals[2], vals[3]);
    } else {
      *(short2*)dst = make_short2(vals[0], vals[1]);
    }
#pragma unroll
    for (int off = 8; off; off >>= 1) {
      s += __shfl_down(s, off, 16);
      q += __shfl_down(q, off, 16);
    }
    if ((tid & 15) == 0) { partS[c][tid >> 4] = s; partQ[c][tid >> 4] = q; }
  }
  __syncthreads();
  for (int c = tid; c < CS; c += 256) {
    long long S = 0, Q = 0;
#pragma unroll
    for (int g = 0; g < 16; g++) { S += partS[c][g]; Q += partQ[c][g]; }
    const int co = cg * CS + c;
    atomicAdd(&stats[2 * co], (unsigned long long)S);
    atomicAdd(&stats[2 * co + 1], (unsigned long long)Q);
  }
}

// ---- BN threshold -> exact integer threshold (verified with f64 fma) -------
// decision(v) = dir ? (v >= T) : (v <= T)  ==  fma(al, v, bt) >= 0 for all
// achievable integer v (|v| <= 2304 << 6000).
__global__ void bin_fin(const unsigned long long* __restrict__ stats,
                        const float* __restrict__ g, const float* __restrict__ be,
                        int2* __restrict__ thri, int Co, double Nel) {
  const int c = blockIdx.x * 64 + threadIdx.x;
  if (c >= Co) return;
  const double S = (double)(long long)stats[2 * c];
  const double Q = (double)(long long)stats[2 * c + 1];
  const double mu = S / Nel, var = Q / Nel - mu * mu;
  const double rr = 1.0 / sqrt(var + 1e-4);
  const double al = (double)g[c] * rr;
  const double bt = (double)be[c] - al * mu;
  int T, dir;
  if (al > 0.0) {
    dir = 1;
    const double t = -bt / al;
    if (t >= 6000.0) T = 6000;
    else if (t <= -6000.0) T = -6000;
    else {
      T = (int)ceil(t);
      if (fma(al, (double)(T - 1), bt) >= 0.0) T -= 1;
      else if (fma(al, (double)T, bt) < 0.0) T += 1;
    }
  } else if (al < 0.0) {
    dir = 0;
    const double t = -bt / al;
    if (t >= 6000.0) T = 6000;
    else if (t <= -6000.0) T = -6000;
    else {
      T = (int)floor(t);
      if (fma(al, (double)(T + 1), bt) >= 0.0) T += 1;
      else if (fma(al, (double)T, bt) < 0.0) T -= 1;
    }
  } else {
    dir = 1;
    T = (bt >= 0.0) ? -6000 : 6000;
  }
  thri[c] = make_int2(T, dir);
}

// ---- binarize (no pool): raw [co][n*P] -> packed A [n*P][CO/32] ----
template <int P, int CO>
__global__ void __launch_bounds__(256) binz2(const short* __restrict__ raw,
                                             const int2* __restrict__ thr,
                                             uint32_t* __restrict__ Aout) {
  constexpr int WDo = CO / 32;
  constexpr size_t NP = (size_t)512 * P;
  constexpr int HALF = 512 * P / 2;
  const int idx = blockIdx.x * 256 + threadIdx.x;
  const int np = (idx % HALF) * 2;
  const int wd = idx / HALF;
  uint32_t wo0 = 0, wo1 = 0;
#pragma unroll
  for (int j = 0; j < 32; j++) {
    const int co = wd * 32 + j;
    const int v2 = *(const int*)&raw[co * NP + np];
    const int v0 = (short)v2, v1 = (short)(v2 >> 16);
    const int2 td = thr[co];
    const bool b0 = td.y ? (v0 >= td.x) : (v0 <= td.x);
    const bool b1 = td.y ? (v1 >= td.x) : (v1 <= td.x);
    wo0 |= (uint32_t)b0 << j;
    wo1 |= (uint32_t)b1 << j;
  }
  Aout[(size_t)np * WDo + wd] = wo0;
  Aout[(size_t)(np + 1) * WDo + wd] = wo1;
}

// ---- binarize + 2x2 maxpool (OR of decisions) ----
template <int Hs, int CO>
__global__ void __launch_bounds__(256) binpool2(const short* __restrict__ raw,
                                                const int2* __restrict__ thr,
                                                uint32_t* __restrict__ Aout) {
  constexpr int Ws = Hs, Ps = Hs * Hs, Ho = Hs / 2, Po = Ho * Ho;
  constexpr int WDo = CO / 32;
  constexpr size_t NP = (size_t)512 * Ps;
  const int idx = blockIdx.x * 256 + threadIdx.x;
  const int npo = idx % (512 * Po);
  const int wd = idx / (512 * Po);
  const int n = npo / Po, po = npo % Po;
  const int ho = po / Ho, wo = po % Ho;
  const int p00 = (2 * ho) * Ws + 2 * wo;
  uint32_t word = 0;
#pragma unroll
  for (int j = 0; j < 32; j++) {
    const int co = wd * 32 + j;
    const short* base = raw + co * NP + (size_t)n * Ps;
    const int t2 = *(const int*)&base[p00];
    const int b2 = *(const int*)&base[p00 + Ws];
    const int v0 = (short)t2, v1 = (short)(t2 >> 16);
    const int v2 = (short)b2, v3 = (short)(b2 >> 16);
    const int2 td = thr[co];
    bool b;
    if (td.y) {
      const int mx = max(max(v0, v1), max(v2, v3));
      b = mx >= td.x;
    } else {
      const int mn = min(min(v0, v1), min(v2, v3));
      b = mn <= td.x;
    }
    word |= (uint32_t)b << j;
  }
  Aout[(size_t)npo * WDo + wd] = word;
}

// ---- head: avgpool(4x4) + binary FC (exact in f32) ----
__global__ void __launch_bounds__(64) head_kern(const uint32_t* __restrict__ A6,
                                                const float* __restrict__ fcw,
                                                const float* __restrict__ fcb,
                                                float* __restrict__ fcout) {
  __shared__ uint32_t aw[128];
  __shared__ float feat[256];
  const int n = blockIdx.x, t = threadIdx.x;
  for (int i = t; i < 128; i += 64) aw[i] = A6[(size_t)n * 128 + i];
  __syncthreads();
#pragma unroll
  for (int k = 0; k < 4; k++) {
    const int c = t * 4 + k;
    const int wd = c >> 5, sh = c & 31;
    int cnt = 0;
#pragma unroll
    for (int pos = 0; pos < 16; pos++) cnt += (aw[pos * 8 + wd] >> sh) & 1;
    feat[c] = (float)(cnt - 8) * 0.125f;  // exact
  }
  __syncthreads();
  if (t < 10) {
    float acc = 0.f;  // all partial sums exactly representable
    for (int c = 0; c < 256; c++) acc += (fcw[t * 256 + c] >= 0.f ? feat[c] : -feat[c]);
    fcout[n * 10 + t] = acc + fcb[t];
  }
}

// ---- bn1d over batch: one block, wave per output channel ----
__global__ void __launch_bounds__(640) bn1d_kern(const float* __restrict__ fcout,
                                                 const float* __restrict__ g7,
                                                 const float* __restrict__ be7,
                                                 float* __restrict__ out) {
  const int t = threadIdx.x, o = t >> 6, lane = t & 63;
  double s = 0.0, q = 0.0;
  float v[8];
#pragma unroll
  for (int i = 0; i < 8; i++) {
    v[i] = fcout[(lane + 64 * i) * 10 + o];
    s += v[i];
    q += (double)v[i] * v[i];
  }
#pragma unroll
  for (int off = 32; off; off >>= 1) {
    s += __shfl_down(s, off);
    q += __shfl_down(q, off);
  }
  s = __shfl(s, 0);
  q = __shfl(q, 0);
  const double mu = s / 512.0, var = q / 512.0 - mu * mu;
  const double r = 1.0 / sqrt(var + 1e-5);
  const double al = (double)g7[o] * r;
  const double bt = (double)be7[o] - al * mu;
#pragma unroll
  for (int i = 0; i < 8; i++) out[(lane + 64 * i) * 10 + o] = (float)fma(al, (double)v[i], bt);
}

extern "C" void kernel_launch(void* const* d_in, const int* in_sizes, int n_in,
                              void* d_out, int out_size, void* d_ws, size_t ws_size,
                              hipStream_t stream) {
  const float* x = (const float*)d_in[0];
  const float* w1 = (const float*)d_in[1];
  const float* g1 = (const float*)d_in[3];
  const float* be1 = (const float*)d_in[4];
  const float* w2 = (const float*)d_in[5];
  const float* g2 = (const float*)d_in[7];
  const float* be2 = (const float*)d_in[8];
  const float* w3 = (const float*)d_in[9];
  const float* g3 = (const float*)d_in[11];
  const float* be3 = (const float*)d_in[12];
  const float* w4 = (const float*)d_in[13];
  const float* g4 = (const float*)d_in[15];
  const float* be4 = (const float*)d_in[16];
  const float* w5 = (const float*)d_in[17];
  const float* g5 = (const float*)d_in[19];
  const float* be5 = (const float*)d_in[20];
  const float* w6 = (const float*)d_in[21];
  const float* g6 = (const float*)d_in[23];
  const float* be6 = (const float*)d_in[24];
  const float* fcw = (const float*)d_in[25];
  const float* fcb = (const float*)d_in[26];
  const float* g7 = (const float*)d_in[27];
  const float* be7 = (const float*)d_in[28];
  float* out = (float*)d_out;

  char* ws = (char*)d_ws;
  size_t off = 0;
  auto take = [&](size_t bytes) -> char* {
    char* p = ws + off;
    off = (off + bytes + 255) & ~(size_t)255;
    return p;
  };
  uint32_t* A1 = (uint32_t*)take((size_t)512 * 1024 * 2 * 4);
  uint32_t* A2 = (uint32_t*)take((size_t)512 * 256 * 2 * 4);
  uint32_t* A3 = (uint32_t*)take((size_t)512 * 256 * 4 * 4);
  uint32_t* A4 = (uint32_t*)take((size_t)512 * 64 * 4 * 4);
  uint32_t* A5 = (uint32_t*)take((size_t)512 * 64 * 8 * 4);
  uint32_t* A6 = (uint32_t*)take((size_t)512 * 16 * 8 * 4);
  uint32_t* Wrec = (uint32_t*)take((size_t)45312 * 4);
  double2* part1 = (double2*)take((size_t)64 * 512 * 16);
  unsigned long long* stats = (unsigned long long*)take((size_t)832 * 2 * 8);
  double2* thrD = (double2*)take((size_t)64 * 16);
  int2* thri = (int2*)take((size_t)832 * 8);
  float* fcout = (float*)take((size_t)512 * 10 * 4);
  short* raw = (short*)take((size_t)64 * 512 * 1024 * 2);
  (void)ws_size; (void)in_sizes; (void)n_in; (void)out_size;

  hipMemsetAsync(stats, 0, 832 * 2 * 8, stream);

  pack_all<<<832, 64, 0, stream>>>(w2, w3, w4, w5, w6, Wrec);

  conv1_p1<<<512, 256, 0, stream>>>(x, w1, part1);
  conv1_fin<<<1, 64, 0, stream>>>(part1, g1, be1, thrD);
  conv1_p2<<<512, 256, 0, stream>>>(x, w1, thrD, A1);

  // L2: 32x32, Ci=64(WD2), CO=64
  bconv2<32, 32, 2, 64, 64, 4, 1><<<dim3(512, 1), 256, 0, stream>>>(A1, Wrec + 0, raw, stats + 0);
  bin_fin<<<1, 64, 0, stream>>>(stats + 0, g2, be2, thri + 0, 64, 512.0 * 1024.0);
  binpool2<32, 64><<<1024, 256, 0, stream>>>(raw, thri + 0, A2);

  // L3: 16x16, Ci=64(WD2), CO=128
  bconv2<16, 16, 2, 128, 64, 2, 2><<<dim3(256, 2), 256, 0, stream>>>(A2, Wrec + 1792, raw, stats + 128);
  bin_fin<<<2, 64, 0, stream>>>(stats + 128, g3, be3, thri + 64, 128, 512.0 * 256.0);
  binz2<256, 128><<<1024, 256, 0, stream>>>(raw, thri + 64, A3);

  // L4: 16x16, Ci=128(WD4), CO=128
  bconv2<16, 16, 4, 128, 64, 2, 2><<<dim3(256, 2), 256, 0, stream>>>(A3, Wrec + 5376, raw, stats + 384);
  bin_fin<<<2, 64, 0, stream>>>(stats + 384, g4, be4, thri + 192, 128, 512.0 * 256.0);
  binpool2<16, 128><<<512, 256, 0, stream>>>(raw, thri + 192, A4);

  // L5: 8x8, Ci=128(WD4), CO=256
  bconv2<8, 8, 4, 256, 32, 2, 8><<<dim3(64, 8), 256, 0, stream>>>(A4, Wrec + 11520, raw, stats + 640);
  bin_fin<<<4, 64, 0, stream>>>(stats + 640, g5, be5, thri + 320, 256, 512.0 * 64.0);
  binz2<64, 256><<<512, 256, 0, stream>>>(raw, thri + 320, A5);

  // L6: 8x8, Ci=256(WD8), CO=256
  bconv2<8, 8, 8, 256, 32, 2, 8><<<dim3(64, 8), 256, 0, stream>>>(A5, Wrec + 23808, raw, stats + 1152);
  bin_fin<<<4, 64, 0, stream>>>(stats + 1152, g6, be6, thri + 576, 256, 512.0 * 64.0);
  binpool2<8, 256><<<256, 256, 0, stream>>>(raw, thri + 576, A6);

  head_kern<<<512, 64, 0, stream>>>(A6, fcw, fcb, fcout);
  bn1d_kern<<<1, 640, 0, stream>>>(fcout, g7, be7, out);
}

// Round 3
// 574.832 us; speedup vs baseline: 1.5781x; 1.1194x over previous
//
#include <hip/hip_runtime.h>
#include <cstdint>

// ---------------------------------------------------------------------------
// BinaryNet forward.  Key identities:
//  * binary_tanh(bn2d(conv+b)) == (alpha*conv + beta >= 0 ? +1 : -1), biases cancel.
//  * binary conv of +-1 values == exact integers via XNOR-popcount.
//  * integer thresholds T (verified with f64 fma at T and T+-1) make the
//    binarize decision bit-identical to the f64 fma compare.
//  * pool(binarize(v)) == threshold on max (alpha>0) or min (alpha<0) of the
//    2x2 block -> bconv_pool stores (min,max) per pooled pixel, exact.
//  * conv1 decisions recomputed in f64 (flip-proof vs f64 reference).
// ---------------------------------------------------------------------------

// ---- merged weight pack: bits + per-tap popcount, record stride R ----------
__global__ void __launch_bounds__(64) pack_all(const float* __restrict__ w2,
                                               const float* __restrict__ w3,
                                               const float* __restrict__ w4,
                                               const float* __restrict__ w5,
                                               const float* __restrict__ w6,
                                               uint32_t* __restrict__ Wr) {
  const int bid = blockIdx.x;
  const float* w; int Ci, base, l;
  if (bid < 64)        { w = w2; Ci = 64;  base = 0;     l = bid; }
  else if (bid < 192)  { w = w3; Ci = 64;  base = 1792;  l = bid - 64; }
  else if (bid < 320)  { w = w4; Ci = 128; base = 5376;  l = bid - 192; }
  else if (bid < 576)  { w = w5; Ci = 128; base = 11520; l = bid - 320; }
  else                 { w = w6; Ci = 256; base = 23808; l = bid - 576; }
  const int WD = Ci >> 5;
  const int R = (9 * WD + 9 + 3) & ~3;
  __shared__ uint32_t wloc[72];
  const int t = threadIdx.x;
  for (int i = t; i < 9 * WD; i += 64) {
    const int k = i / WD, d = i % WD;
    uint32_t bits = 0u;
    for (int j = 0; j < 32; j++)
      bits |= (w[((size_t)l * Ci + d * 32 + j) * 9 + k] >= 0.f ? 1u : 0u) << j;
    wloc[i] = bits;
    Wr[base + (size_t)l * R + i] = bits;
  }
  __syncthreads();
  if (t < 9) {
    int pw = 0;
    for (int d = 0; d < WD; d++) pw += __popc(wloc[t * WD + d]);
    Wr[base + (size_t)l * R + 9 * WD + t] = (uint32_t)pw;
  }
}

// ---- conv1 pass 1: f32 conv, per-(image,channel) double partial stats ----
__global__ void __launch_bounds__(256) conv1_p1(const float* __restrict__ x,
                                                const float* __restrict__ w1,
                                                double2* __restrict__ part) {
  __shared__ float ximg[3][34][34];
  __shared__ float wl[64][28];
  __shared__ double pS[64][4], pQ[64][4];
  const int tid = threadIdx.x, n = blockIdx.x;
  for (int i = tid; i < 3 * 34 * 34; i += 256) ((float*)ximg)[i] = 0.f;
  for (int i = tid; i < 1728; i += 256) wl[i / 27][i % 27] = w1[i];
  __syncthreads();
  const float* xb = x + (size_t)n * 3072;
  for (int i = tid; i < 3072; i += 256) {
    const int c = i >> 10, p = i & 1023;
    ximg[c][(p >> 5) + 1][(p & 31) + 1] = xb[i];
  }
  __syncthreads();
  const int h = tid >> 3, w0 = (tid & 7) * 4;
  const int lane = tid & 63, wv = tid >> 6;
  for (int co = 0; co < 64; co++) {
    float acc[4] = {0.f, 0.f, 0.f, 0.f};
#pragma unroll
    for (int ic = 0; ic < 3; ic++)
#pragma unroll
      for (int ky = 0; ky < 3; ky++) {
        float xr[6];
#pragma unroll
        for (int t = 0; t < 6; t++) xr[t] = ximg[ic][h + ky][w0 + t];
#pragma unroll
        for (int kx = 0; kx < 3; kx++) {
          const float wgt = wl[co][ic * 9 + ky * 3 + kx];
#pragma unroll
          for (int j = 0; j < 4; j++) acc[j] = fmaf(xr[j + kx], wgt, acc[j]);
        }
      }
    double s = (double)acc[0] + acc[1] + acc[2] + acc[3];
    double q = (double)acc[0] * acc[0] + (double)acc[1] * acc[1] +
               (double)acc[2] * acc[2] + (double)acc[3] * acc[3];
#pragma unroll
    for (int off = 32; off; off >>= 1) {
      s += __shfl_down(s, off);
      q += __shfl_down(q, off);
    }
    if (lane == 0) { pS[co][wv] = s; pQ[co][wv] = q; }
  }
  __syncthreads();
  if (tid < 64) {
    const double S = pS[tid][0] + pS[tid][1] + pS[tid][2] + pS[tid][3];
    const double Q = pQ[tid][0] + pQ[tid][1] + pQ[tid][2] + pQ[tid][3];
    part[tid * 512 + n] = make_double2(S, Q);
  }
}

__global__ void conv1_fin(const double2* __restrict__ part, const float* __restrict__ g,
                          const float* __restrict__ be, double2* __restrict__ thr) {
  const int c = threadIdx.x;  // 64
  double S = 0.0, Q = 0.0;
  for (int n = 0; n < 512; n++) { const double2 v = part[c * 512 + n]; S += v.x; Q += v.y; }
  const double Nel = 512.0 * 1024.0;
  const double mu = S / Nel, var = Q / Nel - mu * mu;
  const double r = 1.0 / sqrt(var + 1e-4);
  const double al = (double)g[c] * r;
  const double bt = (double)be[c] - al * mu;
  thr[c] = make_double2(al, bt);
}

// ---- conv1 pass 2: f64 recompute + binarize + bit-pack (layout [n][p][2]) ----
__global__ void __launch_bounds__(256) conv1_p2(const float* __restrict__ x,
                                                const float* __restrict__ w1,
                                                const double2* __restrict__ thr,
                                                uint32_t* __restrict__ A1) {
  __shared__ float ximg[3][34][34];
  __shared__ float wl[64][28];
  __shared__ double2 tl[64];
  const int tid = threadIdx.x, n = blockIdx.x;
  for (int i = tid; i < 3 * 34 * 34; i += 256) ((float*)ximg)[i] = 0.f;
  for (int i = tid; i < 1728; i += 256) wl[i / 27][i % 27] = w1[i];
  for (int i = tid; i < 64; i += 256) tl[i] = thr[i];
  __syncthreads();
  const float* xb = x + (size_t)n * 3072;
  for (int i = tid; i < 3072; i += 256) {
    const int c = i >> 10, p = i & 1023;
    ximg[c][(p >> 5) + 1][(p & 31) + 1] = xb[i];
  }
  __syncthreads();
  const int h = tid >> 3, w0 = (tid & 7) * 4;
  uint32_t wbits[4][2] = {{0u, 0u}, {0u, 0u}, {0u, 0u}, {0u, 0u}};
  for (int co = 0; co < 64; co++) {
    double acc[4] = {0.0, 0.0, 0.0, 0.0};
#pragma unroll
    for (int ic = 0; ic < 3; ic++)
#pragma unroll
      for (int ky = 0; ky < 3; ky++) {
        double xd[6];
#pragma unroll
        for (int t = 0; t < 6; t++) xd[t] = (double)ximg[ic][h + ky][w0 + t];
#pragma unroll
        for (int kx = 0; kx < 3; kx++) {
          const double wgt = (double)wl[co][ic * 9 + ky * 3 + kx];
#pragma unroll
          for (int j = 0; j < 4; j++) acc[j] = fma(xd[j + kx], wgt, acc[j]);
        }
      }
    const double2 ab = tl[co];
    const int wd = co >> 5, sh = co & 31;
#pragma unroll
    for (int j = 0; j < 4; j++)
      if (fma(ab.x, acc[j], ab.y) >= 0.0) wbits[j][wd] |= (1u << sh);
  }
#pragma unroll
  for (int j = 0; j < 4; j++) {
    const int p = h * 32 + w0 + j;
#pragma unroll
    for (int wd = 0; wd < 2; wd++) A1[((size_t)n * 1024 + p) * 2 + wd] = wbits[j][wd];
  }
}

// ---- vector LDS load helper ----
template <int WD>
__device__ __forceinline__ void ldvec(const uint32_t* p, uint32_t* dst) {
  if constexpr (WD == 2) {
    const uint2 v = *(const uint2*)p;
    dst[0] = v.x; dst[1] = v.y;
  } else if constexpr (WD == 4) {
    const uint4 v = *(const uint4*)p;
    dst[0] = v.x; dst[1] = v.y; dst[2] = v.z; dst[3] = v.w;
  } else {
    const uint4 a = *(const uint4*)p, b = *(const uint4*)(p + 4);
    dst[0] = a.x; dst[1] = a.y; dst[2] = a.z; dst[3] = a.w;
    dst[4] = b.x; dst[5] = b.y; dst[6] = b.z; dst[7] = b.w;
  }
}

// ---- binary conv (non-pool layers): window-in-registers, channel-inner ----
template <int H, int W, int WD, int CO, int CS, int PT, int IPB, int NT>
__global__ void __launch_bounds__(NT) bconv2(const uint32_t* __restrict__ Ain,
                                             const uint32_t* __restrict__ Wrec,
                                             short* __restrict__ raw,
                                             unsigned long long* __restrict__ stats) {
  constexpr int P = H * W;
  constexpr int Wp2 = W + 2;
  constexpr int IMGW = (H + 2) * Wp2 * WD;
  constexpr int R = (9 * WD + 9 + 3) & ~3;
  constexpr int CPG = W / PT;
  constexpr int TPI = H * CPG;
  static_assert(TPI * IPB == NT, "bad geometry");
  __shared__ __align__(16) uint32_t img[IPB * IMGW];
  __shared__ __align__(16) uint32_t wl[CS * R];
  __shared__ int partS[CS][NT / 16], partQ[CS][NT / 16];

  const int tid = threadIdx.x;
  const int n0 = blockIdx.x * IPB;
  const int cg = blockIdx.y;

  for (int i = tid; i < IPB * IMGW; i += NT) img[i] = 0u;
  const uint32_t* wsrc = Wrec + (size_t)cg * CS * R;
  for (int i = tid; i < CS * R; i += NT) wl[i] = wsrc[i];
  __syncthreads();
  const uint32_t* src = Ain + (size_t)n0 * P * WD;
  for (int i = tid; i < IPB * P * WD; i += NT) {
    const int d = i & (WD - 1);
    const int pp = i / WD;
    const int p = pp & (P - 1);
    const int im = pp / P;
    const int h = p / W, w = p % W;
    img[im * IMGW + ((h + 1) * Wp2 + (w + 1)) * WD + d] = src[i];
  }
  __syncthreads();

  const int iid = tid / TPI;
  const int r = tid % TPI;
  const int h = r / CPG;
  const int w0 = (r % CPG) * PT;
  const int n = n0 + iid;

  uint32_t win[3][(PT + 2) * WD];
  const uint32_t* imgp = img + iid * IMGW;
#pragma unroll
  for (int ky = 0; ky < 3; ky++) {
    const uint32_t* rp = imgp + ((h + ky) * Wp2 + w0) * WD;
#pragma unroll
    for (int cc = 0; cc < PT + 2; cc++) ldvec<WD>(rp + cc * WD, &win[ky][cc * WD]);
  }

  const int rowm = (h == 0 ? 1 : 0) | (h == H - 1 ? 4 : 0);
  unsigned masks[PT];
#pragma unroll
  for (int j = 0; j < PT; j++) {
    const int w = w0 + j;
    const int colm = (w == 0 ? 1 : 0) | (w == W - 1 ? 4 : 0);
    unsigned m = 0;
#pragma unroll
    for (int ky = 0; ky < 3; ky++)
#pragma unroll
      for (int kx = 0; kx < 3; kx++)
        if ((((rowm >> ky) | (colm >> kx)) & 1) != 0) m |= 1u << (ky * 3 + kx);
    masks[j] = m;
  }

  const int p0 = h * W + w0;
#pragma unroll 2
  for (int c = 0; c < CS; ++c) {
    const uint32_t* rec = wl + c * R;
    int acc[PT];
#pragma unroll
    for (int j = 0; j < PT; j++) acc[j] = 0;
#pragma unroll
    for (int ky = 0; ky < 3; ky++)
#pragma unroll
      for (int kx = 0; kx < 3; kx++) {
        uint32_t wt[WD];
        ldvec<WD>(rec + (ky * 3 + kx) * WD, wt);
#pragma unroll
        for (int j = 0; j < PT; j++)
#pragma unroll
          for (int d = 0; d < WD; d++)
            acc[j] += __popc(win[ky][(j + kx) * WD + d] ^ wt[d]);
      }
    int s = 0, q = 0;
    short vals[PT];
#pragma unroll
    for (int j = 0; j < PT; j++) {
      int val = 32 * WD * 9 - 2 * acc[j];
      unsigned m = masks[j];
      while (m) {
        const int k = __builtin_ctz(m);
        m &= m - 1;
        val += 2 * (int)rec[9 * WD + k] - 32 * WD;
      }
      vals[j] = (short)val;
      s += val;
      q += val * val;
    }
    const size_t co = (size_t)(cg * CS + c);
    short* dst = raw + co * ((size_t)512 * P) + (size_t)n * P + p0;
    if constexpr (PT == 4) {
      *(short4*)dst = make_short4(vals[0], vals[1], vals[2], vals[3]);
    } else {
      *(short2*)dst = make_short2(vals[0], vals[1]);
    }
#pragma unroll
    for (int off = 8; off; off >>= 1) {
      s += __shfl_down(s, off, 16);
      q += __shfl_down(q, off, 16);
    }
    if ((tid & 15) == 0) { partS[c][tid >> 4] = s; partQ[c][tid >> 4] = q; }
  }
  __syncthreads();
  for (int c = tid; c < CS; c += NT) {
    long long S = 0, Q = 0;
#pragma unroll
    for (int g = 0; g < NT / 16; g++) { S += partS[c][g]; Q += partQ[c][g]; }
    const int co = cg * CS + c;
    atomicAdd(&stats[2 * co], (unsigned long long)S);
    atomicAdd(&stats[2 * co + 1], (unsigned long long)Q);
  }
}

// ---- binary conv + fused 2x2 pool prep: stores (min,max) per pooled pixel --
template <int H, int W, int WD, int CO, int CS, int IPB, int NT>
__global__ void __launch_bounds__(NT) bconv_pool(const uint32_t* __restrict__ Ain,
                                                 const uint32_t* __restrict__ Wrec,
                                                 int* __restrict__ mm,
                                                 unsigned long long* __restrict__ stats) {
  constexpr int P = H * W;
  constexpr int Ho = H / 2, Wo = W / 2, Po = Ho * Wo;
  constexpr int Wp2 = W + 2;
  constexpr int IMGW = (H + 2) * Wp2 * WD;
  constexpr int R = (9 * WD + 9 + 3) & ~3;
  constexpr int TPI = Po;
  static_assert(TPI * IPB == NT, "bad geometry");
  __shared__ __align__(16) uint32_t img[IPB * IMGW];
  __shared__ __align__(16) uint32_t wl[CS * R];
  __shared__ int partS[CS][NT / 16], partQ[CS][NT / 16];

  const int tid = threadIdx.x;
  const int n0 = blockIdx.x * IPB;
  const int cg = blockIdx.y;

  for (int i = tid; i < IPB * IMGW; i += NT) img[i] = 0u;
  const uint32_t* wsrc = Wrec + (size_t)cg * CS * R;
  for (int i = tid; i < CS * R; i += NT) wl[i] = wsrc[i];
  __syncthreads();
  const uint32_t* src = Ain + (size_t)n0 * P * WD;
  for (int i = tid; i < IPB * P * WD; i += NT) {
    const int d = i & (WD - 1);
    const int pp = i / WD;
    const int p = pp & (P - 1);
    const int im = pp / P;
    const int h = p / W, w = p % W;
    img[im * IMGW + ((h + 1) * Wp2 + (w + 1)) * WD + d] = src[i];
  }
  __syncthreads();

  const int iid = tid / TPI;
  const int r = tid % TPI;
  const int ho = r / Wo;
  const int wo = r % Wo;
  const int n = n0 + iid;

  // 4x4 window (rows 2ho-1..2ho+2, cols 2wo-1..2wo+2) in registers
  uint32_t win[4][4 * WD];
  const uint32_t* imgp = img + iid * IMGW;
#pragma unroll
  for (int ry = 0; ry < 4; ry++) {
    const uint32_t* rp = imgp + ((2 * ho + ry) * Wp2 + 2 * wo) * WD;
#pragma unroll
    for (int cx = 0; cx < 4; cx++) ldvec<WD>(rp + cx * WD, &win[ry][cx * WD]);
  }

  unsigned masks[4];
#pragma unroll
  for (int dy = 0; dy < 2; dy++)
#pragma unroll
    for (int dx = 0; dx < 2; dx++) {
      const int rowm = ((ho == 0 && dy == 0) ? 1 : 0) | ((ho == Ho - 1 && dy == 1) ? 4 : 0);
      const int colm = ((wo == 0 && dx == 0) ? 1 : 0) | ((wo == Wo - 1 && dx == 1) ? 4 : 0);
      unsigned m = 0;
#pragma unroll
      for (int ky = 0; ky < 3; ky++)
#pragma unroll
        for (int kx = 0; kx < 3; kx++)
          if ((((rowm >> ky) | (colm >> kx)) & 1) != 0) m |= 1u << (ky * 3 + kx);
      masks[dy * 2 + dx] = m;
    }

#pragma unroll 2
  for (int c = 0; c < CS; ++c) {
    const uint32_t* rec = wl + c * R;
    int acc[4] = {0, 0, 0, 0};
#pragma unroll
    for (int ky = 0; ky < 3; ky++)
#pragma unroll
      for (int kx = 0; kx < 3; kx++) {
        uint32_t wt[WD];
        ldvec<WD>(rec + (ky * 3 + kx) * WD, wt);
#pragma unroll
        for (int dy = 0; dy < 2; dy++)
#pragma unroll
          for (int dx = 0; dx < 2; dx++)
#pragma unroll
            for (int d = 0; d < WD; d++)
              acc[dy * 2 + dx] += __popc(win[dy + ky][(dx + kx) * WD + d] ^ wt[d]);
      }
    int s = 0, q = 0, mn = 32767, mx = -32768;
#pragma unroll
    for (int j = 0; j < 4; j++) {
      int val = 32 * WD * 9 - 2 * acc[j];
      unsigned m = masks[j];
      while (m) {
        const int k = __builtin_ctz(m);
        m &= m - 1;
        val += 2 * (int)rec[9 * WD + k] - 32 * WD;
      }
      s += val;
      q += val * val;
      mn = min(mn, val);
      mx = max(mx, val);
    }
    const size_t co = (size_t)(cg * CS + c);
    mm[(co * 512 + (size_t)n) * Po + r] = (int)(((uint32_t)(uint16_t)(short)mx << 16) |
                                                (uint32_t)(uint16_t)(short)mn);
#pragma unroll
    for (int off = 8; off; off >>= 1) {
      s += __shfl_down(s, off, 16);
      q += __shfl_down(q, off, 16);
    }
    if ((tid & 15) == 0) { partS[c][tid >> 4] = s; partQ[c][tid >> 4] = q; }
  }
  __syncthreads();
  for (int c = tid; c < CS; c += NT) {
    long long S = 0, Q = 0;
#pragma unroll
    for (int g = 0; g < NT / 16; g++) { S += partS[c][g]; Q += partQ[c][g]; }
    const int co = cg * CS + c;
    atomicAdd(&stats[2 * co], (unsigned long long)S);
    atomicAdd(&stats[2 * co + 1], (unsigned long long)Q);
  }
}

// ---- BN threshold -> exact integer threshold (verified with f64 fma) -------
__global__ void bin_fin(const unsigned long long* __restrict__ stats,
                        const float* __restrict__ g, const float* __restrict__ be,
                        int2* __restrict__ thri, int Co, double Nel) {
  const int c = blockIdx.x * 64 + threadIdx.x;
  if (c >= Co) return;
  const double S = (double)(long long)stats[2 * c];
  const double Q = (double)(long long)stats[2 * c + 1];
  const double mu = S / Nel, var = Q / Nel - mu * mu;
  const double rr = 1.0 / sqrt(var + 1e-4);
  const double al = (double)g[c] * rr;
  const double bt = (double)be[c] - al * mu;
  int T, dir;
  if (al > 0.0) {
    dir = 1;
    const double t = -bt / al;
    if (t >= 6000.0) T = 6000;
    else if (t <= -6000.0) T = -6000;
    else {
      T = (int)ceil(t);
      if (fma(al, (double)(T - 1), bt) >= 0.0) T -= 1;
      else if (fma(al, (double)T, bt) < 0.0) T += 1;
    }
  } else if (al < 0.0) {
    dir = 0;
    const double t = -bt / al;
    if (t >= 6000.0) T = 6000;
    else if (t <= -6000.0) T = -6000;
    else {
      T = (int)floor(t);
      if (fma(al, (double)(T + 1), bt) >= 0.0) T += 1;
      else if (fma(al, (double)T, bt) < 0.0) T -= 1;
    }
  } else {
    dir = 1;
    T = (bt >= 0.0) ? -6000 : 6000;
  }
  thri[c] = make_int2(T, dir);
}

// ---- binarize (no pool): raw [co][n*P] -> packed A [n*P][CO/32] ----
template <int P, int CO>
__global__ void __launch_bounds__(256) binz2(const short* __restrict__ raw,
                                             const int2* __restrict__ thr,
                                             uint32_t* __restrict__ Aout) {
  constexpr int WDo = CO / 32;
  constexpr size_t NP = (size_t)512 * P;
  constexpr int HALF = 512 * P / 2;
  const int idx = blockIdx.x * 256 + threadIdx.x;
  const int np = (idx % HALF) * 2;
  const int wd = idx / HALF;
  uint32_t wo0 = 0, wo1 = 0;
#pragma unroll
  for (int j = 0; j < 32; j++) {
    const int co = wd * 32 + j;
    const int v2 = *(const int*)&raw[co * NP + np];
    const int v0 = (short)v2, v1 = (short)(v2 >> 16);
    const int2 td = thr[co];
    const bool b0 = td.y ? (v0 >= td.x) : (v0 <= td.x);
    const bool b1 = td.y ? (v1 >= td.x) : (v1 <= td.x);
    wo0 |= (uint32_t)b0 << j;
    wo1 |= (uint32_t)b1 << j;
  }
  Aout[(size_t)np * WDo + wd] = wo0;
  Aout[(size_t)(np + 1) * WDo + wd] = wo1;
}

// ---- pooled binarize from (min,max) planes ----
template <int Po, int CO>
__global__ void __launch_bounds__(256) binpool_mm(const int* __restrict__ mm,
                                                  const int2* __restrict__ thr,
                                                  uint32_t* __restrict__ Aout) {
  constexpr int WDo = CO / 32;
  constexpr size_t NPo = (size_t)512 * Po;
  const int idx = blockIdx.x * 256 + threadIdx.x;
  const int npo = idx % (512 * Po);
  const int wd = idx / (512 * Po);
  uint32_t word = 0;
#pragma unroll
  for (int j = 0; j < 32; j++) {
    const int co = wd * 32 + j;
    const int v = mm[co * NPo + npo];
    const int mn = (short)v, mx = (short)(v >> 16);
    const int2 td = thr[co];
    const bool b = td.y ? (mx >= td.x) : (mn <= td.x);
    word |= (uint32_t)b << j;
  }
  Aout[(size_t)npo * WDo + wd] = word;
}

// ---- head: avgpool(4x4) + binary FC (exact in f32) ----
__global__ void __launch_bounds__(64) head_kern(const uint32_t* __restrict__ A6,
                                                const float* __restrict__ fcw,
                                                const float* __restrict__ fcb,
                                                float* __restrict__ fcout) {
  __shared__ uint32_t aw[128];
  __shared__ float feat[256];
  const int n = blockIdx.x, t = threadIdx.x;
  for (int i = t; i < 128; i += 64) aw[i] = A6[(size_t)n * 128 + i];
  __syncthreads();
#pragma unroll
  for (int k = 0; k < 4; k++) {
    const int c = t * 4 + k;
    const int wd = c >> 5, sh = c & 31;
    int cnt = 0;
#pragma unroll
    for (int pos = 0; pos < 16; pos++) cnt += (aw[pos * 8 + wd] >> sh) & 1;
    feat[c] = (float)(cnt - 8) * 0.125f;  // exact
  }
  __syncthreads();
  if (t < 10) {
    float acc = 0.f;  // all partial sums exactly representable
    for (int c = 0; c < 256; c++) acc += (fcw[t * 256 + c] >= 0.f ? feat[c] : -feat[c]);
    fcout[n * 10 + t] = acc + fcb[t];
  }
}

// ---- bn1d over batch: one block, wave per output channel ----
__global__ void __launch_bounds__(640) bn1d_kern(const float* __restrict__ fcout,
                                                 const float* __restrict__ g7,
                                                 const float* __restrict__ be7,
                                                 float* __restrict__ out) {
  const int t = threadIdx.x, o = t >> 6, lane = t & 63;
  double s = 0.0, q = 0.0;
  float v[8];
#pragma unroll
  for (int i = 0; i < 8; i++) {
    v[i] = fcout[(lane + 64 * i) * 10 + o];
    s += v[i];
    q += (double)v[i] * v[i];
  }
#pragma unroll
  for (int off = 32; off; off >>= 1) {
    s += __shfl_down(s, off);
    q += __shfl_down(q, off);
  }
  s = __shfl(s, 0);
  q = __shfl(q, 0);
  const double mu = s / 512.0, var = q / 512.0 - mu * mu;
  const double r = 1.0 / sqrt(var + 1e-5);
  const double al = (double)g7[o] * r;
  const double bt = (double)be7[o] - al * mu;
#pragma unroll
  for (int i = 0; i < 8; i++) out[(lane + 64 * i) * 10 + o] = (float)fma(al, (double)v[i], bt);
}

extern "C" void kernel_launch(void* const* d_in, const int* in_sizes, int n_in,
                              void* d_out, int out_size, void* d_ws, size_t ws_size,
                              hipStream_t stream) {
  const float* x = (const float*)d_in[0];
  const float* w1 = (const float*)d_in[1];
  const float* g1 = (const float*)d_in[3];
  const float* be1 = (const float*)d_in[4];
  const float* w2 = (const float*)d_in[5];
  const float* g2 = (const float*)d_in[7];
  const float* be2 = (const float*)d_in[8];
  const float* w3 = (const float*)d_in[9];
  const float* g3 = (const float*)d_in[11];
  const float* be3 = (const float*)d_in[12];
  const float* w4 = (const float*)d_in[13];
  const float* g4 = (const float*)d_in[15];
  const float* be4 = (const float*)d_in[16];
  const float* w5 = (const float*)d_in[17];
  const float* g5 = (const float*)d_in[19];
  const float* be5 = (const float*)d_in[20];
  const float* w6 = (const float*)d_in[21];
  const float* g6 = (const float*)d_in[23];
  const float* be6 = (const float*)d_in[24];
  const float* fcw = (const float*)d_in[25];
  const float* fcb = (const float*)d_in[26];
  const float* g7 = (const float*)d_in[27];
  const float* be7 = (const float*)d_in[28];
  float* out = (float*)d_out;

  char* ws = (char*)d_ws;
  size_t off = 0;
  auto take = [&](size_t bytes) -> char* {
    char* p = ws + off;
    off = (off + bytes + 255) & ~(size_t)255;
    return p;
  };
  uint32_t* A1 = (uint32_t*)take((size_t)512 * 1024 * 2 * 4);
  uint32_t* A2 = (uint32_t*)take((size_t)512 * 256 * 2 * 4);
  uint32_t* A3 = (uint32_t*)take((size_t)512 * 256 * 4 * 4);
  uint32_t* A4 = (uint32_t*)take((size_t)512 * 64 * 4 * 4);
  uint32_t* A5 = (uint32_t*)take((size_t)512 * 64 * 8 * 4);
  uint32_t* A6 = (uint32_t*)take((size_t)512 * 16 * 8 * 4);
  uint32_t* Wrec = (uint32_t*)take((size_t)45312 * 4);
  double2* part1 = (double2*)take((size_t)64 * 512 * 16);
  unsigned long long* stats = (unsigned long long*)take((size_t)832 * 2 * 8);
  double2* thrD = (double2*)take((size_t)64 * 16);
  int2* thri = (int2*)take((size_t)832 * 8);
  float* fcout = (float*)take((size_t)512 * 10 * 4);
  short* raw = (short*)take((size_t)64 * 512 * 1024 * 2);
  int* mm = (int*)raw;  // aliased: mm and raw lifetimes don't overlap
  (void)ws_size; (void)in_sizes; (void)n_in; (void)out_size;

  hipMemsetAsync(stats, 0, 832 * 2 * 8, stream);

  pack_all<<<832, 64, 0, stream>>>(w2, w3, w4, w5, w6, Wrec);

  conv1_p1<<<512, 256, 0, stream>>>(x, w1, part1);
  conv1_fin<<<1, 64, 0, stream>>>(part1, g1, be1, thrD);
  conv1_p2<<<512, 256, 0, stream>>>(x, w1, thrD, A1);

  // L2 (pool): 32x32, WD2, CO=64 -> mm planes [co][n][256]
  bconv_pool<32, 32, 2, 64, 16, 1, 256><<<dim3(512, 4), 256, 0, stream>>>(A1, Wrec + 0, mm, stats + 0);
  bin_fin<<<1, 64, 0, stream>>>(stats + 0, g2, be2, thri + 0, 64, 512.0 * 1024.0);
  binpool_mm<256, 64><<<1024, 256, 0, stream>>>(mm, thri + 0, A2);

  // L3 (no pool): 16x16, WD2, CO=128
  bconv2<16, 16, 2, 128, 16, 2, 2, 256><<<dim3(256, 8), 256, 0, stream>>>(A2, Wrec + 1792, raw, stats + 128);
  bin_fin<<<2, 64, 0, stream>>>(stats + 128, g3, be3, thri + 64, 128, 512.0 * 256.0);
  binz2<256, 128><<<1024, 256, 0, stream>>>(raw, thri + 64, A3);

  // L4 (pool): 16x16, WD4, CO=128 -> mm planes [co][n][64]
  bconv_pool<16, 16, 4, 128, 16, 4, 256><<<dim3(128, 8), 256, 0, stream>>>(A3, Wrec + 5376, mm, stats + 384);
  bin_fin<<<2, 64, 0, stream>>>(stats + 384, g4, be4, thri + 192, 128, 512.0 * 256.0);
  binpool_mm<64, 128><<<512, 256, 0, stream>>>(mm, thri + 192, A4);

  // L5 (no pool): 8x8, WD4, CO=256
  bconv2<8, 8, 4, 256, 8, 2, 8, 256><<<dim3(64, 32), 256, 0, stream>>>(A4, Wrec + 11520, raw, stats + 640);
  bin_fin<<<4, 64, 0, stream>>>(stats + 640, g5, be5, thri + 320, 256, 512.0 * 64.0);
  binz2<64, 256><<<512, 256, 0, stream>>>(raw, thri + 320, A5);

  // L6 (pool): 8x8, WD8, CO=256 -> mm planes [co][n][16]
  bconv_pool<8, 8, 8, 256, 8, 8, 128><<<dim3(64, 32), 128, 0, stream>>>(A5, Wrec + 23808, mm, stats + 1152);
  bin_fin<<<4, 64, 0, stream>>>(stats + 1152, g6, be6, thri + 576, 256, 512.0 * 64.0);
  binpool_mm<16, 256><<<256, 256, 0, stream>>>(mm, thri + 576, A6);

  head_kern<<<512, 64, 0, stream>>>(A6, fcw, fcb, fcout);
  bn1d_kern<<<1, 640, 0, stream>>>(fcout, g7, be7, out);
}

// Round 4
// 450.712 us; speedup vs baseline: 2.0127x; 1.2754x over previous
//
#include <hip/hip_runtime.h>
#include <cstdint>

// ---------------------------------------------------------------------------
// BinaryNet forward.  Key identities:
//  * binary_tanh(bn2d(conv+b)) == (alpha*conv + beta >= 0 ? +1 : -1), biases cancel.
//  * binary conv of +-1 values == exact integers via XNOR-popcount.
//  * integer thresholds T (verified with f64 fma at T and T+-1) make the
//    binarize decision bit-identical to the f64 fma compare.
//  * pool(binarize(v)) == threshold on max (alpha>0) or min (alpha<0) of the
//    2x2 block -> bconv_pool stores (min,max) per pooled pixel, exact.
//  * conv1 decisions: f32 conv + certified f64 fallback for |t|<=eps
//    (eps = |alpha|*27*2^-24*Sum|w|*Xmax*1.25 bounds the f32 chain error),
//    fallback recomputes the exact same f64 fma chain as before -> decisions
//    bit-identical to the all-f64 version that passed with absmax 0.
// ---------------------------------------------------------------------------

// Weight record layout per co: [bits k*WD+d : 9*WD words][pad to 4][pwm[9] =
// 2*popc(w_k)-32*WD as int][pad to 4].  R = align4(9WD)+12.
// Bases (words): L2@0 R32, L3@2048 R32, L4@6144 R48, L5@12288 R48, L6@24576 R84.
__global__ void __launch_bounds__(64) pack_all(const float* __restrict__ w2,
                                               const float* __restrict__ w3,
                                               const float* __restrict__ w4,
                                               const float* __restrict__ w5,
                                               const float* __restrict__ w6,
                                               uint32_t* __restrict__ Wr) {
  const int bid = blockIdx.x;
  const float* w; int Ci, base, l;
  if (bid < 64)        { w = w2; Ci = 64;  base = 0;     l = bid; }
  else if (bid < 192)  { w = w3; Ci = 64;  base = 2048;  l = bid - 64; }
  else if (bid < 320)  { w = w4; Ci = 128; base = 6144;  l = bid - 192; }
  else if (bid < 576)  { w = w5; Ci = 128; base = 12288; l = bid - 320; }
  else                 { w = w6; Ci = 256; base = 24576; l = bid - 576; }
  const int WD = Ci >> 5;
  const int PW = (9 * WD + 3) & ~3;
  const int R = PW + 12;
  __shared__ uint32_t wloc[72];
  const int t = threadIdx.x;
  uint32_t* rec = Wr + base + (size_t)l * R;
  for (int i = t; i < 9 * WD; i += 64) {
    const int k = i / WD, d = i % WD;
    uint32_t bits = 0u;
    for (int j = 0; j < 32; j++)
      bits |= (w[((size_t)l * Ci + d * 32 + j) * 9 + k] >= 0.f ? 1u : 0u) << j;
    wloc[i] = bits;
    rec[i] = bits;
  }
  for (int i = 9 * WD + t; i < R; i += 64)
    if (i < PW || i >= PW + 9) rec[i] = 0u;
  __syncthreads();
  if (t < 9) {
    int pw = 0;
    for (int d = 0; d < WD; d++) pw += __popc(wloc[t * WD + d]);
    rec[PW + t] = (uint32_t)(2 * pw - 32 * WD);
  }
}

// ---- conv1 pass 1: f32 conv (window in regs), f64 partial stats ----
__global__ void __launch_bounds__(256) conv1_p1(const float* __restrict__ x,
                                                const float* __restrict__ w1,
                                                double2* __restrict__ part) {
  __shared__ float ximg[3][34][34];
  __shared__ float wl[32][28];
  __shared__ double pS[32][4], pQ[32][4];
  const int tid = threadIdx.x, n = blockIdx.x, cg = blockIdx.y;
  for (int i = tid; i < 3 * 34 * 34; i += 256) ((float*)ximg)[i] = 0.f;
  for (int i = tid; i < 32 * 27; i += 256) wl[i / 27][i % 27] = w1[cg * 864 + i];
  __syncthreads();
  const float* xb = x + (size_t)n * 3072;
  for (int i = tid; i < 3072; i += 256) {
    const int c = i >> 10, p = i & 1023;
    ximg[c][(p >> 5) + 1][(p & 31) + 1] = xb[i];
  }
  __syncthreads();
  const int h = tid >> 3, w0 = (tid & 7) * 4;
  const int lane = tid & 63, wv = tid >> 6;
  float win[3][3][6];
#pragma unroll
  for (int ic = 0; ic < 3; ic++)
#pragma unroll
    for (int ky = 0; ky < 3; ky++)
#pragma unroll
      for (int t = 0; t < 6; t++) win[ic][ky][t] = ximg[ic][h + ky][w0 + t];
  for (int c = 0; c < 32; c++) {
    float4 wv4[7];
#pragma unroll
    for (int i = 0; i < 7; i++) wv4[i] = *(const float4*)&wl[c][i * 4];
    const float* wf = (const float*)wv4;
    float acc[4] = {0.f, 0.f, 0.f, 0.f};
#pragma unroll
    for (int ic = 0; ic < 3; ic++)
#pragma unroll
      for (int ky = 0; ky < 3; ky++)
#pragma unroll
        for (int kx = 0; kx < 3; kx++) {
          const float wgt = wf[ic * 9 + ky * 3 + kx];
#pragma unroll
          for (int j = 0; j < 4; j++) acc[j] = fmaf(win[ic][ky][j + kx], wgt, acc[j]);
        }
    double s = (double)acc[0] + acc[1] + acc[2] + acc[3];
    double q = (double)acc[0] * acc[0] + (double)acc[1] * acc[1] +
               (double)acc[2] * acc[2] + (double)acc[3] * acc[3];
#pragma unroll
    for (int off = 32; off; off >>= 1) {
      s += __shfl_down(s, off);
      q += __shfl_down(q, off);
    }
    if (lane == 0) { pS[c][wv] = s; pQ[c][wv] = q; }
  }
  __syncthreads();
  if (tid < 32) {
    const double S = pS[tid][0] + pS[tid][1] + pS[tid][2] + pS[tid][3];
    const double Q = pQ[tid][0] + pQ[tid][1] + pQ[tid][2] + pQ[tid][3];
    part[(size_t)(cg * 32 + tid) * 512 + n] = make_double2(S, Q);
  }
}

__global__ void conv1_fin(const double2* __restrict__ part, const float* __restrict__ g,
                          const float* __restrict__ be, const float* __restrict__ w1,
                          double2* __restrict__ thr, double* __restrict__ te) {
  const int c = threadIdx.x;  // 64
  double S = 0.0, Q = 0.0;
  for (int n = 0; n < 512; n++) { const double2 v = part[c * 512 + n]; S += v.x; Q += v.y; }
  const double Nel = 512.0 * 1024.0;
  const double mu = S / Nel, var = Q / Nel - mu * mu;
  const double r = 1.0 / sqrt(var + 1e-4);
  const double al = (double)g[c] * r;
  const double bt = (double)be[c] - al * mu;
  thr[c] = make_double2(al, bt);
  double ws = 0.0;
  for (int k = 0; k < 27; k++) ws += fabs((double)w1[c * 27 + k]);
  te[c] = fabs(al) * 27.0 * 5.9604644775390625e-08 * ws * 1.25;
}

// ---- conv1 pass 2: f32 conv + certified f64 fallback, binarize + pack ----
__global__ void __launch_bounds__(256) conv1_p2(const float* __restrict__ x,
                                                const float* __restrict__ w1,
                                                const double2* __restrict__ thr,
                                                const double* __restrict__ te,
                                                uint32_t* __restrict__ A1) {
  __shared__ float ximg[3][34][34];
  __shared__ float wl[32][28];
  __shared__ double2 tl[32];
  __shared__ double tel[32];
  __shared__ float smx[4];
  const int tid = threadIdx.x, n = blockIdx.x, cg = blockIdx.y;
  for (int i = tid; i < 3 * 34 * 34; i += 256) ((float*)ximg)[i] = 0.f;
  for (int i = tid; i < 32 * 27; i += 256) wl[i / 27][i % 27] = w1[cg * 864 + i];
  for (int i = tid; i < 32; i += 256) { tl[i] = thr[cg * 32 + i]; tel[i] = te[cg * 32 + i]; }
  __syncthreads();
  const float* xb = x + (size_t)n * 3072;
  float mx = 0.f;
  for (int i = tid; i < 3072; i += 256) {
    const int c = i >> 10, p = i & 1023;
    const float v = xb[i];
    ximg[c][(p >> 5) + 1][(p & 31) + 1] = v;
    mx = fmaxf(mx, fabsf(v));
  }
  const int lane = tid & 63, wv = tid >> 6;
#pragma unroll
  for (int off = 32; off; off >>= 1) mx = fmaxf(mx, __shfl_xor(mx, off));
  if (lane == 0) smx[wv] = mx;
  __syncthreads();
  const double Xmax = (double)fmaxf(fmaxf(smx[0], smx[1]), fmaxf(smx[2], smx[3]));
  const int h = tid >> 3, w0 = (tid & 7) * 4;
  float win[3][3][6];
#pragma unroll
  for (int ic = 0; ic < 3; ic++)
#pragma unroll
    for (int ky = 0; ky < 3; ky++)
#pragma unroll
      for (int t = 0; t < 6; t++) win[ic][ky][t] = ximg[ic][h + ky][w0 + t];
  uint32_t wbits[4] = {0u, 0u, 0u, 0u};
  for (int c = 0; c < 32; c++) {
    float4 wv4[7];
#pragma unroll
    for (int i = 0; i < 7; i++) wv4[i] = *(const float4*)&wl[c][i * 4];
    const float* wf = (const float*)wv4;
    float acc[4] = {0.f, 0.f, 0.f, 0.f};
#pragma unroll
    for (int ic = 0; ic < 3; ic++)
#pragma unroll
      for (int ky = 0; ky < 3; ky++)
#pragma unroll
        for (int kx = 0; kx < 3; kx++) {
          const float wgt = wf[ic * 9 + ky * 3 + kx];
#pragma unroll
          for (int j = 0; j < 4; j++) acc[j] = fmaf(win[ic][ky][j + kx], wgt, acc[j]);
        }
    const double2 ab = tl[c];
    const double ef = tel[c] * Xmax;
#pragma unroll
    for (int j = 0; j < 4; j++) {
      double t = fma(ab.x, (double)acc[j], ab.y);
      if (fabs(t) <= ef) {  // rare: re-derive exactly (same fma order as all-f64)
        double a64 = 0.0;
        for (int k = 0; k < 27; k++) {
          const int ic = k / 9, rr = k % 9, ky = rr / 3, kx = rr % 3;
          a64 = fma((double)ximg[ic][h + ky][w0 + j + kx], (double)wl[c][k], a64);
        }
        t = fma(ab.x, a64, ab.y);
      }
      if (t >= 0.0) wbits[j] |= 1u << c;
    }
  }
#pragma unroll
  for (int j = 0; j < 4; j++) {
    const int p = h * 32 + w0 + j;
    A1[((size_t)n * 1024 + p) * 2 + cg] = wbits[j];
  }
}

// ---- vector LDS load helper ----
template <int WD>
__device__ __forceinline__ void ldvec(const uint32_t* p, uint32_t* dst) {
  if constexpr (WD == 2) {
    const uint2 v = *(const uint2*)p;
    dst[0] = v.x; dst[1] = v.y;
  } else if constexpr (WD == 4) {
    const uint4 v = *(const uint4*)p;
    dst[0] = v.x; dst[1] = v.y; dst[2] = v.z; dst[3] = v.w;
  } else {
    const uint4 a = *(const uint4*)p, b = *(const uint4*)(p + 4);
    dst[0] = a.x; dst[1] = a.y; dst[2] = a.z; dst[3] = a.w;
    dst[4] = b.x; dst[5] = b.y; dst[6] = b.z; dst[7] = b.w;
  }
}

// ---- boundary-first thread maps (concentrate border lanes in few waves) ----
template <int H, int W, int PT, int REMAP>
__device__ __forceinline__ void map_conv(int idx, int& iid, int& h, int& w0) {
  if constexpr (REMAP == 3) {  // 16x16, PT=2, IPB=2: 88 border then interior
    if (idx < 88) {
      iid = idx / 44; const int b = idx % 44;
      if (b < 8)       { h = 0;  w0 = 2 * b; }
      else if (b < 16) { h = 15; w0 = 2 * (b - 8); }
      else if (b < 30) { h = b - 15; w0 = 0; }
      else             { h = b - 29; w0 = 14; }
    } else {
      const int t = idx - 88; iid = t / 84; const int i = t % 84;
      h = 1 + i / 6; w0 = 2 + 2 * (i % 6);
    }
  } else if constexpr (REMAP == 4) {  // 8x8, PT=2, IPB=8: 160 border then interior
    if (idx < 160) {
      iid = idx / 20; const int b = idx % 20;
      if (b < 4)       { h = 0; w0 = 2 * b; }
      else if (b < 8)  { h = 7; w0 = 2 * (b - 4); }
      else if (b < 14) { h = b - 7; w0 = 0; }
      else             { h = b - 13; w0 = 6; }
    } else {
      const int t = idx - 160; iid = t / 12; const int i = t % 12;
      h = 1 + i / 2; w0 = 2 + 2 * (i % 2);
    }
  } else {
    constexpr int CPG = W / PT, TPI = H * CPG;
    iid = idx / TPI; const int r = idx % TPI;
    h = r / CPG; w0 = (r % CPG) * PT;
  }
}

template <int Ho, int REMAP>
__device__ __forceinline__ void map_pool(int idx, int& iid, int& ho, int& wo) {
  if constexpr (REMAP == 1) {  // 16x16 pooled, IPB=1: ring(60) then interior
    iid = 0;
    if (idx < 16)      { ho = 0;  wo = idx; }
    else if (idx < 32) { ho = 15; wo = idx - 16; }
    else if (idx < 46) { ho = idx - 31; wo = 0; }
    else if (idx < 60) { ho = idx - 45; wo = 15; }
    else { const int i = idx - 60; ho = 1 + i / 14; wo = 1 + i % 14; }
  } else if constexpr (REMAP == 2) {  // 8x8 pooled, IPB=4: 112 border then interior
    if (idx < 112) {
      iid = idx / 28; const int b = idx % 28;
      if (b < 8)       { ho = 0; wo = b; }
      else if (b < 16) { ho = 7; wo = b - 8; }
      else if (b < 22) { ho = b - 15; wo = 0; }
      else             { ho = b - 21; wo = 7; }
    } else {
      const int t = idx - 112; iid = t / 36; const int i = t % 36;
      ho = 1 + i / 6; wo = 1 + i % 6;
    }
  } else {
    constexpr int Po = Ho * Ho;
    iid = idx / Po; const int r = idx % Po;
    ho = r / Ho; wo = r % Ho;
  }
}

// ---- binary conv (non-pool): window-in-registers, channel-inner ----
template <int H, int W, int WD, int CO, int CS, int PT, int IPB, int NT, int REMAP>
__global__ void __launch_bounds__(NT) bconv2(const uint32_t* __restrict__ Ain,
                                             const uint32_t* __restrict__ Wrec,
                                             short* __restrict__ raw,
                                             unsigned long long* __restrict__ stats) {
  constexpr int P = H * W;
  constexpr int Wp2 = W + 2;
  constexpr int IMGW = (H + 2) * Wp2 * WD;
  constexpr int PW = (9 * WD + 3) & ~3;
  constexpr int R = PW + 12;
  static_assert(H * (W / PT) * IPB == NT, "bad geometry");
  __shared__ __align__(16) uint32_t img[IPB * IMGW];
  __shared__ __align__(16) uint32_t wl[CS * R];
  __shared__ int partS[CS][NT / 16], partQ[CS][NT / 16];

  const int tid = threadIdx.x;
  const int n0 = blockIdx.x * IPB;
  const int cg = blockIdx.y;

  for (int i = tid; i < IPB * IMGW; i += NT) img[i] = 0u;
  const uint32_t* wsrc = Wrec + (size_t)cg * CS * R;
  for (int i = tid; i < CS * R; i += NT) wl[i] = wsrc[i];
  __syncthreads();
  const uint32_t* src = Ain + (size_t)n0 * P * WD;
  for (int i = tid; i < IPB * P * WD; i += NT) {
    const int d = i & (WD - 1);
    const int pp = i / WD;
    const int p = pp & (P - 1);
    const int im = pp / P;
    const int h = p / W, w = p % W;
    img[im * IMGW + ((h + 1) * Wp2 + (w + 1)) * WD + d] = src[i];
  }
  __syncthreads();

  int iid, h, w0;
  map_conv<H, W, PT, REMAP>(tid, iid, h, w0);
  const int n = n0 + iid;

  uint32_t win[3][(PT + 2) * WD];
  const uint32_t* imgp = img + iid * IMGW;
#pragma unroll
  for (int ky = 0; ky < 3; ky++) {
    const uint32_t* rp = imgp + ((h + ky) * Wp2 + w0) * WD;
#pragma unroll
    for (int cc = 0; cc < PT + 2; cc++) ldvec<WD>(rp + cc * WD, &win[ky][cc * WD]);
  }

  const int rowm = (h == 0 ? 1 : 0) | (h == H - 1 ? 4 : 0);
  unsigned masks[PT];
  unsigned mall = 0;
#pragma unroll
  for (int j = 0; j < PT; j++) {
    const int w = w0 + j;
    const int colm = (w == 0 ? 1 : 0) | (w == W - 1 ? 4 : 0);
    unsigned m = 0;
#pragma unroll
    for (int ky = 0; ky < 3; ky++)
#pragma unroll
      for (int kx = 0; kx < 3; kx++)
        if ((((rowm >> ky) | (colm >> kx)) & 1) != 0) m |= 1u << (ky * 3 + kx);
    masks[j] = m;
    mall |= m;
  }
  const bool waveB = __any((int)(mall != 0));

  const int p0 = h * W + w0;
#pragma unroll 2
  for (int c = 0; c < CS; ++c) {
    const uint32_t* rec = wl + c * R;
    uint32_t wrec[WD == 2 ? 20 : 1];
    if constexpr (WD == 2) {
#pragma unroll
      for (int i = 0; i < 5; i++) ldvec<4>(rec + i * 4, &wrec[i * 4]);
    }
    int acc[PT];
#pragma unroll
    for (int j = 0; j < PT; j++) acc[j] = 0;
#pragma unroll
    for (int ky = 0; ky < 3; ky++)
#pragma unroll
      for (int kx = 0; kx < 3; kx++) {
        uint32_t wt[WD];
        if constexpr (WD == 2) {
          wt[0] = wrec[(ky * 3 + kx) * 2];
          wt[1] = wrec[(ky * 3 + kx) * 2 + 1];
        } else {
          ldvec<WD>(rec + (ky * 3 + kx) * WD, wt);
        }
#pragma unroll
        for (int j = 0; j < PT; j++)
#pragma unroll
          for (int d = 0; d < WD; d++)
            acc[j] += __popc(win[ky][(j + kx) * WD + d] ^ wt[d]);
      }
    int val[PT];
#pragma unroll
    for (int j = 0; j < PT; j++) val[j] = 32 * WD * 9 - 2 * acc[j];
    if (waveB) {
      int pwm[12];
#pragma unroll
      for (int i = 0; i < 3; i++) ldvec<4>(rec + PW + i * 4, (uint32_t*)&pwm[i * 4]);
#pragma unroll
      for (int j = 0; j < PT; j++) {
        int corr = 0;
#pragma unroll
        for (int k = 0; k < 9; k++) corr += (int)((masks[j] >> k) & 1u) * pwm[k];
        val[j] += corr;
      }
    }
    int s = 0, q = 0;
#pragma unroll
    for (int j = 0; j < PT; j++) { s += val[j]; q += val[j] * val[j]; }
    const size_t co = (size_t)(cg * CS + c);
    short* dst = raw + co * ((size_t)512 * P) + (size_t)n * P + p0;
    *(short2*)dst = make_short2((short)val[0], (short)val[1]);
#pragma unroll
    for (int off = 8; off; off >>= 1) {
      s += __shfl_down(s, off, 16);
      q += __shfl_down(q, off, 16);
    }
    if ((tid & 15) == 0) { partS[c][tid >> 4] = s; partQ[c][tid >> 4] = q; }
  }
  __syncthreads();
  for (int c = tid; c < CS; c += NT) {
    long long S = 0, Q = 0;
#pragma unroll
    for (int g = 0; g < NT / 16; g++) { S += partS[c][g]; Q += partQ[c][g]; }
    const int co = cg * CS + c;
    atomicAdd(&stats[2 * co], (unsigned long long)S);
    atomicAdd(&stats[2 * co + 1], (unsigned long long)Q);
  }
}

// ---- binary conv + fused 2x2 pool prep: stores (min,max) per pooled pixel --
template <int H, int W, int WD, int CO, int CS, int IPB, int NT, int REMAP>
__global__ void __launch_bounds__(NT) bconv_pool(const uint32_t* __restrict__ Ain,
                                                 const uint32_t* __restrict__ Wrec,
                                                 int* __restrict__ mm,
                                                 unsigned long long* __restrict__ stats) {
  constexpr int P = H * W;
  constexpr int Ho = H / 2, Wo = W / 2, Po = Ho * Wo;
  constexpr int Wp2 = W + 2;
  constexpr int IMGW = (H + 2) * Wp2 * WD;
  constexpr int PW = (9 * WD + 3) & ~3;
  constexpr int R = PW + 12;
  static_assert(Po * IPB == NT, "bad geometry");
  __shared__ __align__(16) uint32_t img[IPB * IMGW];
  __shared__ __align__(16) uint32_t wl[CS * R];
  __shared__ int partS[CS][NT / 16], partQ[CS][NT / 16];

  const int tid = threadIdx.x;
  const int n0 = blockIdx.x * IPB;
  const int cg = blockIdx.y;

  for (int i = tid; i < IPB * IMGW; i += NT) img[i] = 0u;
  const uint32_t* wsrc = Wrec + (size_t)cg * CS * R;
  for (int i = tid; i < CS * R; i += NT) wl[i] = wsrc[i];
  __syncthreads();
  const uint32_t* src = Ain + (size_t)n0 * P * WD;
  for (int i = tid; i < IPB * P * WD; i += NT) {
    const int d = i & (WD - 1);
    const int pp = i / WD;
    const int p = pp & (P - 1);
    const int im = pp / P;
    const int h = p / W, w = p % W;
    img[im * IMGW + ((h + 1) * Wp2 + (w + 1)) * WD + d] = src[i];
  }
  __syncthreads();

  int iid, ho, wo;
  map_pool<Ho, REMAP>(tid, iid, ho, wo);
  const int n = n0 + iid;
  const int pout = ho * Wo + wo;

  uint32_t win[4][4 * WD];
  const uint32_t* imgp = img + iid * IMGW;
#pragma unroll
  for (int ry = 0; ry < 4; ry++) {
    const uint32_t* rp = imgp + ((2 * ho + ry) * Wp2 + 2 * wo) * WD;
#pragma unroll
    for (int cx = 0; cx < 4; cx++) ldvec<WD>(rp + cx * WD, &win[ry][cx * WD]);
  }

  unsigned masks[4];
  unsigned mall = 0;
#pragma unroll
  for (int dy = 0; dy < 2; dy++)
#pragma unroll
    for (int dx = 0; dx < 2; dx++) {
      const int rowm = ((ho == 0 && dy == 0) ? 1 : 0) | ((ho == Ho - 1 && dy == 1) ? 4 : 0);
      const int colm = ((wo == 0 && dx == 0) ? 1 : 0) | ((wo == Wo - 1 && dx == 1) ? 4 : 0);
      unsigned m = 0;
#pragma unroll
      for (int ky = 0; ky < 3; ky++)
#pragma unroll
        for (int kx = 0; kx < 3; kx++)
          if ((((rowm >> ky) | (colm >> kx)) & 1) != 0) m |= 1u << (ky * 3 + kx);
      masks[dy * 2 + dx] = m;
      mall |= m;
    }
  const bool waveB = __any((int)(mall != 0));

#pragma unroll 2
  for (int c = 0; c < CS; ++c) {
    const uint32_t* rec = wl + c * R;
    uint32_t wrec[WD == 2 ? 20 : 1];
    if constexpr (WD == 2) {
#pragma unroll
      for (int i = 0; i < 5; i++) ldvec<4>(rec + i * 4, &wrec[i * 4]);
    }
    int acc[4] = {0, 0, 0, 0};
#pragma unroll
    for (int ky = 0; ky < 3; ky++)
#pragma unroll
      for (int kx = 0; kx < 3; kx++) {
        uint32_t wt[WD];
        if constexpr (WD == 2) {
          wt[0] = wrec[(ky * 3 + kx) * 2];
          wt[1] = wrec[(ky * 3 + kx) * 2 + 1];
        } else {
          ldvec<WD>(rec + (ky * 3 + kx) * WD, wt);
        }
#pragma unroll
        for (int dy = 0; dy < 2; dy++)
#pragma unroll
          for (int dx = 0; dx < 2; dx++)
#pragma unroll
            for (int d = 0; d < WD; d++)
              acc[dy * 2 + dx] += __popc(win[dy + ky][(dx + kx) * WD + d] ^ wt[d]);
      }
    int val[4];
#pragma unroll
    for (int j = 0; j < 4; j++) val[j] = 32 * WD * 9 - 2 * acc[j];
    if (waveB) {
      int pwm[12];
#pragma unroll
      for (int i = 0; i < 3; i++) ldvec<4>(rec + PW + i * 4, (uint32_t*)&pwm[i * 4]);
#pragma unroll
      for (int j = 0; j < 4; j++) {
        int corr = 0;
#pragma unroll
        for (int k = 0; k < 9; k++) corr += (int)((masks[j] >> k) & 1u) * pwm[k];
        val[j] += corr;
      }
    }
    int s = 0, q = 0, mn = 32767, mxv = -32768;
#pragma unroll
    for (int j = 0; j < 4; j++) {
      s += val[j];
      q += val[j] * val[j];
      mn = min(mn, val[j]);
      mxv = max(mxv, val[j]);
    }
    const size_t co = (size_t)(cg * CS + c);
    mm[(co * 512 + (size_t)n) * Po + pout] = (int)(((uint32_t)(uint16_t)(short)mxv << 16) |
                                                   (uint32_t)(uint16_t)(short)mn);
#pragma unroll
    for (int off = 8; off; off >>= 1) {
      s += __shfl_down(s, off, 16);
      q += __shfl_down(q, off, 16);
    }
    if ((tid & 15) == 0) { partS[c][tid >> 4] = s; partQ[c][tid >> 4] = q; }
  }
  __syncthreads();
  for (int c = tid; c < CS; c += NT) {
    long long S = 0, Q = 0;
#pragma unroll
    for (int g = 0; g < NT / 16; g++) { S += partS[c][g]; Q += partQ[c][g]; }
    const int co = cg * CS + c;
    atomicAdd(&stats[2 * co], (unsigned long long)S);
    atomicAdd(&stats[2 * co + 1], (unsigned long long)Q);
  }
}

// ---- BN threshold -> exact integer threshold (verified with f64 fma) -------
__global__ void bin_fin(const unsigned long long* __restrict__ stats,
                        const float* __restrict__ g, const float* __restrict__ be,
                        int2* __restrict__ thri, int Co, double Nel) {
  const int c = blockIdx.x * 64 + threadIdx.x;
  if (c >= Co) return;
  const double S = (double)(long long)stats[2 * c];
  const double Q = (double)(long long)stats[2 * c + 1];
  const double mu = S / Nel, var = Q / Nel - mu * mu;
  const double rr = 1.0 / sqrt(var + 1e-4);
  const double al = (double)g[c] * rr;
  const double bt = (double)be[c] - al * mu;
  int T, dir;
  if (al > 0.0) {
    dir = 1;
    const double t = -bt / al;
    if (t >= 6000.0) T = 6000;
    else if (t <= -6000.0) T = -6000;
    else {
      T = (int)ceil(t);
      if (fma(al, (double)(T - 1), bt) >= 0.0) T -= 1;
      else if (fma(al, (double)T, bt) < 0.0) T += 1;
    }
  } else if (al < 0.0) {
    dir = 0;
    const double t = -bt / al;
    if (t >= 6000.0) T = 6000;
    else if (t <= -6000.0) T = -6000;
    else {
      T = (int)floor(t);
      if (fma(al, (double)(T + 1), bt) >= 0.0) T += 1;
      else if (fma(al, (double)T, bt) < 0.0) T -= 1;
    }
  } else {
    dir = 1;
    T = (bt >= 0.0) ? -6000 : 6000;
  }
  thri[c] = make_int2(T, dir);
}

// ---- binarize (no pool): raw [co][n*P] -> packed A [n*P][CO/32] ----
template <int P, int CO>
__global__ void __launch_bounds__(256) binz2(const short* __restrict__ raw,
                                             const int2* __restrict__ thr,
                                             uint32_t* __restrict__ Aout) {
  constexpr int WDo = CO / 32;
  constexpr size_t NP = (size_t)512 * P;
  constexpr int HALF = 512 * P / 2;
  const int idx = blockIdx.x * 256 + threadIdx.x;
  const int np = (idx % HALF) * 2;
  const int wd = idx / HALF;
  uint32_t wo0 = 0, wo1 = 0;
#pragma unroll
  for (int j = 0; j < 32; j++) {
    const int co = wd * 32 + j;
    const int v2 = *(const int*)&raw[co * NP + np];
    const int v0 = (short)v2, v1 = (short)(v2 >> 16);
    const int2 td = thr[co];
    const bool b0 = td.y ? (v0 >= td.x) : (v0 <= td.x);
    const bool b1 = td.y ? (v1 >= td.x) : (v1 <= td.x);
    wo0 |= (uint32_t)b0 << j;
    wo1 |= (uint32_t)b1 << j;
  }
  Aout[(size_t)np * WDo + wd] = wo0;
  Aout[(size_t)(np + 1) * WDo + wd] = wo1;
}

// ---- pooled binarize from (min,max) planes ----
template <int Po, int CO>
__global__ void __launch_bounds__(256) binpool_mm(const int* __restrict__ mm,
                                                  const int2* __restrict__ thr,
                                                  uint32_t* __restrict__ Aout) {
  constexpr int WDo = CO / 32;
  constexpr size_t NPo = (size_t)512 * Po;
  const int idx = blockIdx.x * 256 + threadIdx.x;
  const int npo = idx % (512 * Po);
  const int wd = idx / (512 * Po);
  uint32_t word = 0;
#pragma unroll
  for (int j = 0; j < 32; j++) {
    const int co = wd * 32 + j;
    const int v = mm[co * NPo + npo];
    const int mn = (short)v, mx = (short)(v >> 16);
    const int2 td = thr[co];
    const bool b = td.y ? (mx >= td.x) : (mn <= td.x);
    word |= (uint32_t)b << j;
  }
  Aout[(size_t)npo * WDo + wd] = word;
}

// ---- head: avgpool(4x4) + binary FC (exact in f32) ----
__global__ void __launch_bounds__(64) head_kern(const uint32_t* __restrict__ A6,
                                                const float* __restrict__ fcw,
                                                const float* __restrict__ fcb,
                                                float* __restrict__ fcout) {
  __shared__ uint32_t aw[128];
  __shared__ float feat[256];
  const int n = blockIdx.x, t = threadIdx.x;
  for (int i = t; i < 128; i += 64) aw[i] = A6[(size_t)n * 128 + i];
  __syncthreads();
#pragma unroll
  for (int k = 0; k < 4; k++) {
    const int c = t * 4 + k;
    const int wd = c >> 5, sh = c & 31;
    int cnt = 0;
#pragma unroll
    for (int pos = 0; pos < 16; pos++) cnt += (aw[pos * 8 + wd] >> sh) & 1;
    feat[c] = (float)(cnt - 8) * 0.125f;  // exact
  }
  __syncthreads();
  if (t < 10) {
    float acc = 0.f;  // all partial sums exactly representable
    for (int c = 0; c < 256; c++) acc += (fcw[t * 256 + c] >= 0.f ? feat[c] : -feat[c]);
    fcout[n * 10 + t] = acc + fcb[t];
  }
}

// ---- bn1d over batch: one block, wave per output channel ----
__global__ void __launch_bounds__(640) bn1d_kern(const float* __restrict__ fcout,
                                                 const float* __restrict__ g7,
                                                 const float* __restrict__ be7,
                                                 float* __restrict__ out) {
  const int t = threadIdx.x, o = t >> 6, lane = t & 63;
  double s = 0.0, q = 0.0;
  float v[8];
#pragma unroll
  for (int i = 0; i < 8; i++) {
    v[i] = fcout[(lane + 64 * i) * 10 + o];
    s += v[i];
    q += (double)v[i] * v[i];
  }
#pragma unroll
  for (int off = 32; off; off >>= 1) {
    s += __shfl_down(s, off);
    q += __shfl_down(q, off);
  }
  s = __shfl(s, 0);
  q = __shfl(q, 0);
  const double mu = s / 512.0, var = q / 512.0 - mu * mu;
  const double r = 1.0 / sqrt(var + 1e-5);
  const double al = (double)g7[o] * r;
  const double bt = (double)be7[o] - al * mu;
#pragma unroll
  for (int i = 0; i < 8; i++) out[(lane + 64 * i) * 10 + o] = (float)fma(al, (double)v[i], bt);
}

extern "C" void kernel_launch(void* const* d_in, const int* in_sizes, int n_in,
                              void* d_out, int out_size, void* d_ws, size_t ws_size,
                              hipStream_t stream) {
  const float* x = (const float*)d_in[0];
  const float* w1 = (const float*)d_in[1];
  const float* g1 = (const float*)d_in[3];
  const float* be1 = (const float*)d_in[4];
  const float* w2 = (const float*)d_in[5];
  const float* g2 = (const float*)d_in[7];
  const float* be2 = (const float*)d_in[8];
  const float* w3 = (const float*)d_in[9];
  const float* g3 = (const float*)d_in[11];
  const float* be3 = (const float*)d_in[12];
  const float* w4 = (const float*)d_in[13];
  const float* g4 = (const float*)d_in[15];
  const float* be4 = (const float*)d_in[16];
  const float* w5 = (const float*)d_in[17];
  const float* g5 = (const float*)d_in[19];
  const float* be5 = (const float*)d_in[20];
  const float* w6 = (const float*)d_in[21];
  const float* g6 = (const float*)d_in[23];
  const float* be6 = (const float*)d_in[24];
  const float* fcw = (const float*)d_in[25];
  const float* fcb = (const float*)d_in[26];
  const float* g7 = (const float*)d_in[27];
  const float* be7 = (const float*)d_in[28];
  float* out = (float*)d_out;

  char* ws = (char*)d_ws;
  size_t off = 0;
  auto take = [&](size_t bytes) -> char* {
    char* p = ws + off;
    off = (off + bytes + 255) & ~(size_t)255;
    return p;
  };
  uint32_t* A1 = (uint32_t*)take((size_t)512 * 1024 * 2 * 4);
  uint32_t* A2 = (uint32_t*)take((size_t)512 * 256 * 2 * 4);
  uint32_t* A3 = (uint32_t*)take((size_t)512 * 256 * 4 * 4);
  uint32_t* A4 = (uint32_t*)take((size_t)512 * 64 * 4 * 4);
  uint32_t* A5 = (uint32_t*)take((size_t)512 * 64 * 8 * 4);
  uint32_t* A6 = (uint32_t*)take((size_t)512 * 16 * 8 * 4);
  uint32_t* Wrec = (uint32_t*)take((size_t)46080 * 4);
  double2* part1 = (double2*)take((size_t)64 * 512 * 16);
  unsigned long long* stats = (unsigned long long*)take((size_t)832 * 2 * 8);
  double2* thrD = (double2*)take((size_t)64 * 16);
  double* teD = (double*)take((size_t)64 * 8);
  int2* thri = (int2*)take((size_t)832 * 8);
  float* fcout = (float*)take((size_t)512 * 10 * 4);
  short* raw = (short*)take((size_t)64 * 512 * 1024 * 2);
  int* mm = (int*)raw;  // aliased: mm and raw lifetimes don't overlap
  (void)ws_size; (void)in_sizes; (void)n_in; (void)out_size;

  hipMemsetAsync(stats, 0, 832 * 2 * 8, stream);

  pack_all<<<832, 64, 0, stream>>>(w2, w3, w4, w5, w6, Wrec);

  conv1_p1<<<dim3(512, 2), 256, 0, stream>>>(x, w1, part1);
  conv1_fin<<<1, 64, 0, stream>>>(part1, g1, be1, w1, thrD, teD);
  conv1_p2<<<dim3(512, 2), 256, 0, stream>>>(x, w1, thrD, teD, A1);

  // L2 (pool): 32x32, WD2, CO=64 -> mm planes [co][n][256]
  bconv_pool<32, 32, 2, 64, 16, 1, 256, 1><<<dim3(512, 4), 256, 0, stream>>>(A1, Wrec + 0, mm, stats + 0);
  bin_fin<<<1, 64, 0, stream>>>(stats + 0, g2, be2, thri + 0, 64, 512.0 * 1024.0);
  binpool_mm<256, 64><<<1024, 256, 0, stream>>>(mm, thri + 0, A2);

  // L3 (no pool): 16x16, WD2, CO=128
  bconv2<16, 16, 2, 128, 16, 2, 2, 256, 3><<<dim3(256, 8), 256, 0, stream>>>(A2, Wrec + 2048, raw, stats + 128);
  bin_fin<<<2, 64, 0, stream>>>(stats + 128, g3, be3, thri + 64, 128, 512.0 * 256.0);
  binz2<256, 128><<<1024, 256, 0, stream>>>(raw, thri + 64, A3);

  // L4 (pool): 16x16, WD4, CO=128 -> mm planes [co][n][64]
  bconv_pool<16, 16, 4, 128, 16, 4, 256, 2><<<dim3(128, 8), 256, 0, stream>>>(A3, Wrec + 6144, mm, stats + 384);
  bin_fin<<<2, 64, 0, stream>>>(stats + 384, g4, be4, thri + 192, 128, 512.0 * 256.0);
  binpool_mm<64, 128><<<512, 256, 0, stream>>>(mm, thri + 192, A4);

  // L5 (no pool): 8x8, WD4, CO=256
  bconv2<8, 8, 4, 256, 8, 2, 8, 256, 4><<<dim3(64, 32), 256, 0, stream>>>(A4, Wrec + 12288, raw, stats + 640);
  bin_fin<<<4, 64, 0, stream>>>(stats + 640, g5, be5, thri + 320, 256, 512.0 * 64.0);
  binz2<64, 256><<<512, 256, 0, stream>>>(raw, thri + 320, A5);

  // L6 (pool): 8x8, WD8, CO=256 -> mm planes [co][n][16]
  bconv_pool<8, 8, 8, 256, 8, 4, 64, 0><<<dim3(128, 32), 64, 0, stream>>>(A5, Wrec + 24576, mm, stats + 1152);
  bin_fin<<<4, 64, 0, stream>>>(stats + 1152, g6, be6, thri + 576, 256, 512.0 * 64.0);
  binpool_mm<16, 256><<<256, 256, 0, stream>>>(mm, thri + 576, A6);

  head_kern<<<512, 64, 0, stream>>>(A6, fcw, fcb, fcout);
  bn1d_kern<<<1, 640, 0, stream>>>(fcout, g7, be7, out);
}

// Round 5
// 439.686 us; speedup vs baseline: 2.0632x; 1.0251x over previous
//
#include <hip/hip_runtime.h>
#include <cstdint>

// ---------------------------------------------------------------------------
// BinaryNet forward.  Key identities:
//  * binary_tanh(bn2d(conv+b)) == (alpha*conv + beta >= 0 ? +1 : -1), biases cancel.
//  * binary conv of +-1 values == exact integers via XNOR-popcount.
//  * integer thresholds T (verified with f64 fma at T and T+-1) make the
//    binarize decision bit-identical to the f64 fma compare.
//  * pool(binarize(v)) == threshold on max (alpha>0) or min (alpha<0) of the
//    2x2 block -> pool convs store (min,max) per pooled pixel, exact.
//  * zero-padded taps contribute (32WD-2pw_k); subtracting => border correction
//    = sum of pwm_k over invalid taps; only 9 (rowclass x colclass) patterns
//    exist -> precomputed per-channel 9-entry table, exact integers.
//  * conv1 decisions: f32 conv + certified f64 fallback for |t|<=eps.
// ---------------------------------------------------------------------------

// Weight record per co: [bits k*WD+d : 9*WD][pad to PW][corr[9] class table][pad].
// R = PW+12. Bases (words): L2@0 R32, L3@2048 R32, L4@6144 R48, L5@12288 R48,
// L6@24576 R84.
__global__ void __launch_bounds__(64) pack_all(const float* __restrict__ w2,
                                               const float* __restrict__ w3,
                                               const float* __restrict__ w4,
                                               const float* __restrict__ w5,
                                               const float* __restrict__ w6,
                                               uint32_t* __restrict__ Wr) {
  const int bid = blockIdx.x;
  const float* w; int Ci, base, l;
  if (bid < 64)        { w = w2; Ci = 64;  base = 0;     l = bid; }
  else if (bid < 192)  { w = w3; Ci = 64;  base = 2048;  l = bid - 64; }
  else if (bid < 320)  { w = w4; Ci = 128; base = 6144;  l = bid - 192; }
  else if (bid < 576)  { w = w5; Ci = 128; base = 12288; l = bid - 320; }
  else                 { w = w6; Ci = 256; base = 24576; l = bid - 576; }
  const int WD = Ci >> 5;
  const int PW = (9 * WD + 3) & ~3;
  const int R = PW + 12;
  __shared__ uint32_t wloc[72];
  __shared__ int pwm_sh[9];
  const int t = threadIdx.x;
  uint32_t* rec = Wr + base + (size_t)l * R;
  for (int i = t; i < 9 * WD; i += 64) {
    const int k = i / WD, d = i % WD;
    uint32_t bits = 0u;
    for (int j = 0; j < 32; j++)
      bits |= (w[((size_t)l * Ci + d * 32 + j) * 9 + k] >= 0.f ? 1u : 0u) << j;
    wloc[i] = bits;
    rec[i] = bits;
  }
  for (int i = 9 * WD + t; i < R; i += 64)
    if (i < PW || i >= PW + 9) rec[i] = 0u;
  __syncthreads();
  if (t < 9) {
    int pw = 0;
    for (int d = 0; d < WD; d++) pw += __popc(wloc[t * WD + d]);
    pwm_sh[t] = 2 * pw - 32 * WD;
  }
  __syncthreads();
  if (t < 9) {
    const int rmi = t / 3, cmi = t % 3;
    const int rm = (rmi == 0) ? 1 : (rmi == 1 ? 0 : 4);
    const int cm = (cmi == 0) ? 1 : (cmi == 1 ? 0 : 4);
    int corr = 0;
    for (int ky = 0; ky < 3; ky++)
      for (int kx = 0; kx < 3; kx++)
        if ((((rm >> ky) | (cm >> kx)) & 1) != 0) corr += pwm_sh[ky * 3 + kx];
    rec[PW + t] = (uint32_t)corr;
  }
}

// ---- conv1 pass 1: f32 conv (window in regs), f64 partial stats ----
__global__ void __launch_bounds__(256, 4) conv1_p1(const float* __restrict__ x,
                                                   const float* __restrict__ w1,
                                                   double2* __restrict__ part) {
  __shared__ float ximg[3][34][34];
  __shared__ float wl[32][28];
  __shared__ double pS[32][4], pQ[32][4];
  const int tid = threadIdx.x, n = blockIdx.x, cg = blockIdx.y;
  for (int i = tid; i < 3 * 34 * 34; i += 256) ((float*)ximg)[i] = 0.f;
  for (int i = tid; i < 32 * 27; i += 256) wl[i / 27][i % 27] = w1[cg * 864 + i];
  __syncthreads();
  const float* xb = x + (size_t)n * 3072;
  for (int i = tid; i < 3072; i += 256) {
    const int c = i >> 10, p = i & 1023;
    ximg[c][(p >> 5) + 1][(p & 31) + 1] = xb[i];
  }
  __syncthreads();
  const int h = tid >> 3, w0 = (tid & 7) * 4;
  const int lane = tid & 63, wv = tid >> 6;
  float win[3][3][6];
#pragma unroll
  for (int ic = 0; ic < 3; ic++)
#pragma unroll
    for (int ky = 0; ky < 3; ky++)
#pragma unroll
      for (int t = 0; t < 6; t++) win[ic][ky][t] = ximg[ic][h + ky][w0 + t];
  for (int c = 0; c < 32; c++) {
    float4 wv4[7];
#pragma unroll
    for (int i = 0; i < 7; i++) wv4[i] = *(const float4*)&wl[c][i * 4];
    const float* wf = (const float*)wv4;
    float acc[4] = {0.f, 0.f, 0.f, 0.f};
#pragma unroll
    for (int ic = 0; ic < 3; ic++)
#pragma unroll
      for (int ky = 0; ky < 3; ky++)
#pragma unroll
        for (int kx = 0; kx < 3; kx++) {
          const float wgt = wf[ic * 9 + ky * 3 + kx];
#pragma unroll
          for (int j = 0; j < 4; j++) acc[j] = fmaf(win[ic][ky][j + kx], wgt, acc[j]);
        }
    double s = (double)acc[0] + acc[1] + acc[2] + acc[3];
    double q = (double)acc[0] * acc[0] + (double)acc[1] * acc[1] +
               (double)acc[2] * acc[2] + (double)acc[3] * acc[3];
#pragma unroll
    for (int off = 32; off; off >>= 1) {
      s += __shfl_down(s, off);
      q += __shfl_down(q, off);
    }
    if (lane == 0) { pS[c][wv] = s; pQ[c][wv] = q; }
  }
  __syncthreads();
  if (tid < 32) {
    const double S = pS[tid][0] + pS[tid][1] + pS[tid][2] + pS[tid][3];
    const double Q = pQ[tid][0] + pQ[tid][1] + pQ[tid][2] + pQ[tid][3];
    part[(size_t)(cg * 32 + tid) * 512 + n] = make_double2(S, Q);
  }
}

__global__ void conv1_fin(const double2* __restrict__ part, const float* __restrict__ g,
                          const float* __restrict__ be, const float* __restrict__ w1,
                          double2* __restrict__ thr, double* __restrict__ te) {
  const int c = threadIdx.x;  // 64
  double S = 0.0, Q = 0.0;
  for (int n = 0; n < 512; n++) { const double2 v = part[c * 512 + n]; S += v.x; Q += v.y; }
  const double Nel = 512.0 * 1024.0;
  const double mu = S / Nel, var = Q / Nel - mu * mu;
  const double r = 1.0 / sqrt(var + 1e-4);
  const double al = (double)g[c] * r;
  const double bt = (double)be[c] - al * mu;
  thr[c] = make_double2(al, bt);
  double ws = 0.0;
  for (int k = 0; k < 27; k++) ws += fabs((double)w1[c * 27 + k]);
  te[c] = fabs(al) * 27.0 * 5.9604644775390625e-08 * ws * 1.25;
}

// ---- conv1 pass 2: f32 conv + certified f64 fallback, binarize + pack ----
__global__ void __launch_bounds__(256, 4) conv1_p2(const float* __restrict__ x,
                                                   const float* __restrict__ w1,
                                                   const double2* __restrict__ thr,
                                                   const double* __restrict__ te,
                                                   uint32_t* __restrict__ A1) {
  __shared__ float ximg[3][34][34];
  __shared__ float wl[32][28];
  __shared__ double2 tl[32];
  __shared__ double tel[32];
  __shared__ float smx[4];
  const int tid = threadIdx.x, n = blockIdx.x, cg = blockIdx.y;
  for (int i = tid; i < 3 * 34 * 34; i += 256) ((float*)ximg)[i] = 0.f;
  for (int i = tid; i < 32 * 27; i += 256) wl[i / 27][i % 27] = w1[cg * 864 + i];
  for (int i = tid; i < 32; i += 256) { tl[i] = thr[cg * 32 + i]; tel[i] = te[cg * 32 + i]; }
  __syncthreads();
  const float* xb = x + (size_t)n * 3072;
  float mx = 0.f;
  for (int i = tid; i < 3072; i += 256) {
    const int c = i >> 10, p = i & 1023;
    const float v = xb[i];
    ximg[c][(p >> 5) + 1][(p & 31) + 1] = v;
    mx = fmaxf(mx, fabsf(v));
  }
  const int lane = tid & 63, wv = tid >> 6;
#pragma unroll
  for (int off = 32; off; off >>= 1) mx = fmaxf(mx, __shfl_xor(mx, off));
  if (lane == 0) smx[wv] = mx;
  __syncthreads();
  const double Xmax = (double)fmaxf(fmaxf(smx[0], smx[1]), fmaxf(smx[2], smx[3]));
  const int h = tid >> 3, w0 = (tid & 7) * 4;
  float win[3][3][6];
#pragma unroll
  for (int ic = 0; ic < 3; ic++)
#pragma unroll
    for (int ky = 0; ky < 3; ky++)
#pragma unroll
      for (int t = 0; t < 6; t++) win[ic][ky][t] = ximg[ic][h + ky][w0 + t];
  uint32_t wbits[4] = {0u, 0u, 0u, 0u};
  for (int c = 0; c < 32; c++) {
    float4 wv4[7];
#pragma unroll
    for (int i = 0; i < 7; i++) wv4[i] = *(const float4*)&wl[c][i * 4];
    const float* wf = (const float*)wv4;
    float acc[4] = {0.f, 0.f, 0.f, 0.f};
#pragma unroll
    for (int ic = 0; ic < 3; ic++)
#pragma unroll
      for (int ky = 0; ky < 3; ky++)
#pragma unroll
        for (int kx = 0; kx < 3; kx++) {
          const float wgt = wf[ic * 9 + ky * 3 + kx];
#pragma unroll
          for (int j = 0; j < 4; j++) acc[j] = fmaf(win[ic][ky][j + kx], wgt, acc[j]);
        }
    const double2 ab = tl[c];
    const double ef = tel[c] * Xmax;
#pragma unroll
    for (int j = 0; j < 4; j++) {
      double t = fma(ab.x, (double)acc[j], ab.y);
      if (fabs(t) <= ef) {  // rare: re-derive exactly (same fma order as all-f64)
        double a64 = 0.0;
        for (int k = 0; k < 27; k++) {
          const int ic = k / 9, rr = k % 9, ky = rr / 3, kx = rr % 3;
          a64 = fma((double)ximg[ic][h + ky][w0 + j + kx], (double)wl[c][k], a64);
        }
        t = fma(ab.x, a64, ab.y);
      }
      if (t >= 0.0) wbits[j] |= 1u << c;
    }
  }
#pragma unroll
  for (int j = 0; j < 4; j++) {
    const int p = h * 32 + w0 + j;
    A1[((size_t)n * 1024 + p) * 2 + cg] = wbits[j];
  }
}

// ---- vector LDS load helper ----
template <int WD>
__device__ __forceinline__ void ldvec(const uint32_t* p, uint32_t* dst) {
  if constexpr (WD == 2) {
    const uint2 v = *(const uint2*)p;
    dst[0] = v.x; dst[1] = v.y;
  } else if constexpr (WD == 4) {
    const uint4 v = *(const uint4*)p;
    dst[0] = v.x; dst[1] = v.y; dst[2] = v.z; dst[3] = v.w;
  } else {
    const uint4 a = *(const uint4*)p, b = *(const uint4*)(p + 4);
    dst[0] = a.x; dst[1] = a.y; dst[2] = a.z; dst[3] = a.w;
    dst[4] = b.x; dst[5] = b.y; dst[6] = b.z; dst[7] = b.w;
  }
}

// ---- binary conv (non-pool): window-in-registers, channel-inner ----
template <int H, int W, int WD, int CS, int PT, int IPB, int NT, int MWE>
__global__ void __launch_bounds__(NT, MWE) bconv2(const uint32_t* __restrict__ Ain,
                                                  const uint32_t* __restrict__ Wrec,
                                                  short* __restrict__ raw,
                                                  unsigned long long* __restrict__ stats) {
  constexpr int P = H * W;
  constexpr int Wp2 = W + 2;
  constexpr int IMGW = (H + 2) * Wp2 * WD;
  constexpr int PW = (9 * WD + 3) & ~3;
  constexpr int R = PW + 12;
  constexpr int CPG = W / PT;
  constexpr int TPI = H * CPG;
  static_assert(TPI * IPB == NT, "bad geometry");
  __shared__ __align__(16) uint32_t img[IPB * IMGW];
  __shared__ __align__(16) uint32_t wl[CS * R];
  __shared__ int partS[CS][NT / 16], partQ[CS][NT / 16];

  const int tid = threadIdx.x;
  const int n0 = blockIdx.x * IPB;
  const int cg = blockIdx.y;

  for (int i = tid; i < IPB * IMGW; i += NT) img[i] = 0u;
  const uint32_t* wsrc = Wrec + (size_t)cg * CS * R;
  for (int i = tid; i < CS * R; i += NT) wl[i] = wsrc[i];
  __syncthreads();
  const uint32_t* src = Ain + (size_t)n0 * P * WD;
  for (int i = tid; i < IPB * P * WD; i += NT) {
    const int d = i & (WD - 1);
    const int pp = i / WD;
    const int p = pp & (P - 1);
    const int im = pp / P;
    const int h = p / W, w = p % W;
    img[im * IMGW + ((h + 1) * Wp2 + (w + 1)) * WD + d] = src[i];
  }
  __syncthreads();

  const int iid = tid / TPI;
  const int rr0 = tid % TPI;
  const int h = rr0 / CPG;
  const int w0 = (rr0 % CPG) * PT;
  const int n = n0 + iid;

  uint32_t win[3][(PT + 2) * WD];
  const uint32_t* imgp = img + iid * IMGW;
#pragma unroll
  for (int ky = 0; ky < 3; ky++) {
    const uint32_t* rp = imgp + ((h + ky) * Wp2 + w0) * WD;
#pragma unroll
    for (int cc = 0; cc < PT + 2; cc++) ldvec<WD>(rp + cc * WD, &win[ky][cc * WD]);
  }

  const int rmi = (h == 0) ? 0 : ((h == H - 1) ? 2 : 1);
  int cls[PT];
#pragma unroll
  for (int j = 0; j < PT; j++) {
    const int w = w0 + j;
    cls[j] = rmi * 3 + ((w == 0) ? 0 : ((w == W - 1) ? 2 : 1));
  }

  const int p0 = h * W + w0;
#pragma unroll 2
  for (int c = 0; c < CS; ++c) {
    const uint32_t* rec = wl + c * R;
    int acc[PT];
#pragma unroll
    for (int j = 0; j < PT; j++) acc[j] = 0;
#pragma unroll
    for (int ky = 0; ky < 3; ky++)
#pragma unroll
      for (int kx = 0; kx < 3; kx++) {
        uint32_t wt[WD];
        ldvec<WD>(rec + (ky * 3 + kx) * WD, wt);
#pragma unroll
        for (int j = 0; j < PT; j++)
#pragma unroll
          for (int d = 0; d < WD; d++)
            acc[j] += __popc(win[ky][(j + kx) * WD + d] ^ wt[d]);
      }
    int val[PT];
    int s = 0, q = 0;
#pragma unroll
    for (int j = 0; j < PT; j++) {
      val[j] = 32 * WD * 9 - 2 * acc[j] + (int)rec[PW + cls[j]];
      s += val[j];
      q += val[j] * val[j];
    }
    const size_t co = (size_t)(cg * CS + c);
    short* dst = raw + co * ((size_t)512 * P) + (size_t)n * P + p0;
    *(short2*)dst = make_short2((short)val[0], (short)val[1]);
#pragma unroll
    for (int off = 8; off; off >>= 1) {
      s += __shfl_down(s, off, 16);
      q += __shfl_down(q, off, 16);
    }
    if ((tid & 15) == 0) { partS[c][tid >> 4] = s; partQ[c][tid >> 4] = q; }
  }
  __syncthreads();
  for (int c = tid; c < CS; c += NT) {
    long long S = 0, Q = 0;
#pragma unroll
    for (int g = 0; g < NT / 16; g++) { S += partS[c][g]; Q += partQ[c][g]; }
    const int co = cg * CS + c;
    atomicAdd(&stats[2 * co], (unsigned long long)S);
    atomicAdd(&stats[2 * co + 1], (unsigned long long)Q);
  }
}

// ---- binary conv + fused 2x2 pool prep (L2, L4): (min,max) per pooled px ---
template <int H, int W, int WD, int CS, int IPB, int NT, int MWE>
__global__ void __launch_bounds__(NT, MWE) bconv_pool(const uint32_t* __restrict__ Ain,
                                                      const uint32_t* __restrict__ Wrec,
                                                      int* __restrict__ mm,
                                                      unsigned long long* __restrict__ stats) {
  constexpr int P = H * W;
  constexpr int Ho = H / 2, Wo = W / 2, Po = Ho * Wo;
  constexpr int Wp2 = W + 2;
  constexpr int IMGW = (H + 2) * Wp2 * WD;
  constexpr int PW = (9 * WD + 3) & ~3;
  constexpr int R = PW + 12;
  static_assert(Po * IPB == NT, "bad geometry");
  __shared__ __align__(16) uint32_t img[IPB * IMGW];
  __shared__ __align__(16) uint32_t wl[CS * R];
  __shared__ int partS[CS][NT / 16], partQ[CS][NT / 16];

  const int tid = threadIdx.x;
  const int n0 = blockIdx.x * IPB;
  const int cg = blockIdx.y;

  for (int i = tid; i < IPB * IMGW; i += NT) img[i] = 0u;
  const uint32_t* wsrc = Wrec + (size_t)cg * CS * R;
  for (int i = tid; i < CS * R; i += NT) wl[i] = wsrc[i];
  __syncthreads();
  const uint32_t* src = Ain + (size_t)n0 * P * WD;
  for (int i = tid; i < IPB * P * WD; i += NT) {
    const int d = i & (WD - 1);
    const int pp = i / WD;
    const int p = pp & (P - 1);
    const int im = pp / P;
    const int h = p / W, w = p % W;
    img[im * IMGW + ((h + 1) * Wp2 + (w + 1)) * WD + d] = src[i];
  }
  __syncthreads();

  const int iid = tid / Po;
  const int rr0 = tid % Po;
  const int ho = rr0 / Wo;
  const int wo = rr0 % Wo;
  const int n = n0 + iid;

  uint32_t win[4][4 * WD];
  const uint32_t* imgp = img + iid * IMGW;
#pragma unroll
  for (int ry = 0; ry < 4; ry++) {
    const uint32_t* rp = imgp + ((2 * ho + ry) * Wp2 + 2 * wo) * WD;
#pragma unroll
    for (int cx = 0; cx < 4; cx++) ldvec<WD>(rp + cx * WD, &win[ry][cx * WD]);
  }

  int cls[4];
#pragma unroll
  for (int dy = 0; dy < 2; dy++)
#pragma unroll
    for (int dx = 0; dx < 2; dx++) {
      const int rmi = (ho == 0 && dy == 0) ? 0 : ((ho == Ho - 1 && dy == 1) ? 2 : 1);
      const int cmi = (wo == 0 && dx == 0) ? 0 : ((wo == Wo - 1 && dx == 1) ? 2 : 1);
      cls[dy * 2 + dx] = rmi * 3 + cmi;
    }

#pragma unroll 2
  for (int c = 0; c < CS; ++c) {
    const uint32_t* rec = wl + c * R;
    int acc[4] = {0, 0, 0, 0};
#pragma unroll
    for (int ky = 0; ky < 3; ky++)
#pragma unroll
      for (int kx = 0; kx < 3; kx++) {
        uint32_t wt[WD];
        ldvec<WD>(rec + (ky * 3 + kx) * WD, wt);
#pragma unroll
        for (int dy = 0; dy < 2; dy++)
#pragma unroll
          for (int dx = 0; dx < 2; dx++)
#pragma unroll
            for (int d = 0; d < WD; d++)
              acc[dy * 2 + dx] += __popc(win[dy + ky][(dx + kx) * WD + d] ^ wt[d]);
      }
    int s = 0, q = 0, mn = 32767, mxv = -32768;
#pragma unroll
    for (int j = 0; j < 4; j++) {
      const int val = 32 * WD * 9 - 2 * acc[j] + (int)rec[PW + cls[j]];
      s += val;
      q += val * val;
      mn = min(mn, val);
      mxv = max(mxv, val);
    }
    const size_t co = (size_t)(cg * CS + c);
    mm[(co * 512 + (size_t)n) * Po + rr0] = (int)(((uint32_t)(uint16_t)(short)mxv << 16) |
                                                  (uint32_t)(uint16_t)(short)mn);
#pragma unroll
    for (int off = 8; off; off >>= 1) {
      s += __shfl_down(s, off, 16);
      q += __shfl_down(q, off, 16);
    }
    if ((tid & 15) == 0) { partS[c][tid >> 4] = s; partQ[c][tid >> 4] = q; }
  }
  __syncthreads();
  for (int c = tid; c < CS; c += NT) {
    long long S = 0, Q = 0;
#pragma unroll
    for (int g = 0; g < NT / 16; g++) { S += partS[c][g]; Q += partQ[c][g]; }
    const int co = cg * CS + c;
    atomicAdd(&stats[2 * co], (unsigned long long)S);
    atomicAdd(&stats[2 * co + 1], (unsigned long long)Q);
  }
}

// ---- L6: 8x8 WD=8 pool; WD split over 4 lanes (2 words each), quartet
//      reduce via packed 16-bit shfl_xor (popc partials <=576, exact). ----
template <int CS, int IPB, int MWE>
__global__ void __launch_bounds__(IPB * 64, MWE)
bconv6(const uint32_t* __restrict__ Ain, const uint32_t* __restrict__ Wrec,
       int* __restrict__ mm, unsigned long long* __restrict__ stats) {
  constexpr int WD = 8, W = 8, P = 64, Wo = 4, Po = 16;
  constexpr int Wp2 = 10, IMGW = 10 * 10 * WD;  // 800
  constexpr int PW = 72, R = 84;
  constexpr int NT = IPB * 64;
  __shared__ __align__(16) uint32_t img[IPB * IMGW];
  __shared__ __align__(16) uint32_t wl[CS * R];
  __shared__ int partS[CS][IPB], partQ[CS][IPB];

  const int tid = threadIdx.x;
  const int n0 = blockIdx.x * IPB;
  const int cg = blockIdx.y;

  for (int i = tid; i < IPB * IMGW; i += NT) img[i] = 0u;
  const uint32_t* wsrc = Wrec + (size_t)cg * CS * R;
  for (int i = tid; i < CS * R; i += NT) wl[i] = wsrc[i];
  __syncthreads();
  const uint32_t* src = Ain + (size_t)n0 * P * WD;
  for (int i = tid; i < IPB * P * WD; i += NT) {
    const int d = i & 7;
    const int pp = i >> 3;
    const int p = pp & 63;
    const int im = pp >> 6;
    img[im * IMGW + (((p >> 3) + 1) * Wp2 + (p & 7) + 1) * WD + d] = src[i];
  }
  __syncthreads();

  const int iid = tid >> 6;    // wave == image
  const int lane = tid & 63;
  const int px = lane >> 2;    // pooled pixel 0..15
  const int q = lane & 3;      // WD quarter
  const int ho = px >> 2, wo = px & 3;
  const int n = n0 + iid;

  uint32_t win[4][4][2];
  const uint32_t* imgp = img + iid * IMGW;
#pragma unroll
  for (int ry = 0; ry < 4; ry++)
#pragma unroll
    for (int cx = 0; cx < 4; cx++) {
      const uint2 v = *(const uint2*)(imgp + ((2 * ho + ry) * Wp2 + 2 * wo + cx) * WD + 2 * q);
      win[ry][cx][0] = v.x;
      win[ry][cx][1] = v.y;
    }

  int cls[4];
#pragma unroll
  for (int dy = 0; dy < 2; dy++)
#pragma unroll
    for (int dx = 0; dx < 2; dx++) {
      const int rmi = (ho == 0 && dy == 0) ? 0 : ((ho == 3 && dy == 1) ? 2 : 1);
      const int cmi = (wo == 0 && dx == 0) ? 0 : ((wo == 3 && dx == 1) ? 2 : 1);
      cls[dy * 2 + dx] = rmi * 3 + cmi;
    }

#pragma unroll 2
  for (int c = 0; c < CS; ++c) {
    const uint32_t* rec = wl + c * R;
    int acc[4] = {0, 0, 0, 0};
#pragma unroll
    for (int ky = 0; ky < 3; ky++)
#pragma unroll
      for (int kx = 0; kx < 3; kx++) {
        const uint2 wt = *(const uint2*)(rec + (ky * 3 + kx) * WD + 2 * q);
#pragma unroll
        for (int dy = 0; dy < 2; dy++)
#pragma unroll
          for (int dx = 0; dx < 2; dx++)
            acc[dy * 2 + dx] += __popc(win[dy + ky][dx + kx][0] ^ wt.x) +
                                __popc(win[dy + ky][dx + kx][1] ^ wt.y);
      }
    uint32_t v01 = (uint32_t)acc[0] | ((uint32_t)acc[1] << 16);
    uint32_t v23 = (uint32_t)acc[2] | ((uint32_t)acc[3] << 16);
    v01 += __shfl_xor(v01, 1); v23 += __shfl_xor(v23, 1);
    v01 += __shfl_xor(v01, 2); v23 += __shfl_xor(v23, 2);
    int val[4];
    val[0] = 2304 - 2 * (int)(v01 & 0xFFFFu) + (int)rec[PW + cls[0]];
    val[1] = 2304 - 2 * (int)(v01 >> 16)     + (int)rec[PW + cls[1]];
    val[2] = 2304 - 2 * (int)(v23 & 0xFFFFu) + (int)rec[PW + cls[2]];
    val[3] = 2304 - 2 * (int)(v23 >> 16)     + (int)rec[PW + cls[3]];
    // stats: lane q owns val[q]; 64 lanes cover all 64 conv outputs once
    int sv = val[q], qv = val[q] * val[q];
#pragma unroll
    for (int off = 1; off < 64; off <<= 1) {
      sv += __shfl_xor(sv, off);
      qv += __shfl_xor(qv, off);
    }
    if (lane == 0) { partS[c][iid] = sv; partQ[c][iid] = qv; }
    if (q == 0) {
      const int mn = min(min(val[0], val[1]), min(val[2], val[3]));
      const int mx = max(max(val[0], val[1]), max(val[2], val[3]));
      mm[((size_t)(cg * CS + c) * 512 + n) * Po + px] =
          (int)(((uint32_t)(uint16_t)(short)mx << 16) | (uint32_t)(uint16_t)(short)mn);
    }
  }
  __syncthreads();
  for (int c = tid; c < CS; c += NT) {
    long long S = 0, Q = 0;
#pragma unroll
    for (int g = 0; g < IPB; g++) { S += partS[c][g]; Q += partQ[c][g]; }
    const int co = cg * CS + c;
    atomicAdd(&stats[2 * co], (unsigned long long)S);
    atomicAdd(&stats[2 * co + 1], (unsigned long long)Q);
  }
}

// ---- BN threshold -> exact integer threshold (verified with f64 fma) -------
__global__ void bin_fin(const unsigned long long* __restrict__ stats,
                        const float* __restrict__ g, const float* __restrict__ be,
                        int2* __restrict__ thri, int Co, double Nel) {
  const int c = blockIdx.x * 64 + threadIdx.x;
  if (c >= Co) return;
  const double S = (double)(long long)stats[2 * c];
  const double Q = (double)(long long)stats[2 * c + 1];
  const double mu = S / Nel, var = Q / Nel - mu * mu;
  const double rr = 1.0 / sqrt(var + 1e-4);
  const double al = (double)g[c] * rr;
  const double bt = (double)be[c] - al * mu;
  int T, dir;
  if (al > 0.0) {
    dir = 1;
    const double t = -bt / al;
    if (t >= 6000.0) T = 6000;
    else if (t <= -6000.0) T = -6000;
    else {
      T = (int)ceil(t);
      if (fma(al, (double)(T - 1), bt) >= 0.0) T -= 1;
      else if (fma(al, (double)T, bt) < 0.0) T += 1;
    }
  } else if (al < 0.0) {
    dir = 0;
    const double t = -bt / al;
    if (t >= 6000.0) T = 6000;
    else if (t <= -6000.0) T = -6000;
    else {
      T = (int)floor(t);
      if (fma(al, (double)(T + 1), bt) >= 0.0) T += 1;
      else if (fma(al, (double)T, bt) < 0.0) T -= 1;
    }
  } else {
    dir = 1;
    T = (bt >= 0.0) ? -6000 : 6000;
  }
  thri[c] = make_int2(T, dir);
}

// ---- binarize (no pool): raw [co][n*P] -> packed A [n*P][CO/32] ----
template <int P, int CO>
__global__ void __launch_bounds__(256) binz2(const short* __restrict__ raw,
                                             const int2* __restrict__ thr,
                                             uint32_t* __restrict__ Aout) {
  constexpr int WDo = CO / 32;
  constexpr size_t NP = (size_t)512 * P;
  constexpr int HALF = 512 * P / 2;
  const int idx = blockIdx.x * 256 + threadIdx.x;
  const int np = (idx % HALF) * 2;
  const int wd = idx / HALF;
  uint32_t wo0 = 0, wo1 = 0;
#pragma unroll
  for (int j = 0; j < 32; j++) {
    const int co = wd * 32 + j;
    const int v2 = *(const int*)&raw[co * NP + np];
    const int v0 = (short)v2, v1 = (short)(v2 >> 16);
    const int2 td = thr[co];
    const bool b0 = td.y ? (v0 >= td.x) : (v0 <= td.x);
    const bool b1 = td.y ? (v1 >= td.x) : (v1 <= td.x);
    wo0 |= (uint32_t)b0 << j;
    wo1 |= (uint32_t)b1 << j;
  }
  Aout[(size_t)np * WDo + wd] = wo0;
  Aout[(size_t)(np + 1) * WDo + wd] = wo1;
}

// ---- pooled binarize from (min,max) planes ----
template <int Po, int CO>
__global__ void __launch_bounds__(256) binpool_mm(const int* __restrict__ mm,
                                                  const int2* __restrict__ thr,
                                                  uint32_t* __restrict__ Aout) {
  constexpr int WDo = CO / 32;
  constexpr size_t NPo = (size_t)512 * Po;
  const int idx = blockIdx.x * 256 + threadIdx.x;
  const int npo = idx % (512 * Po);
  const int wd = idx / (512 * Po);
  uint32_t word = 0;
#pragma unroll
  for (int j = 0; j < 32; j++) {
    const int co = wd * 32 + j;
    const int v = mm[co * NPo + npo];
    const int mn = (short)v, mx = (short)(v >> 16);
    const int2 td = thr[co];
    const bool b = td.y ? (mx >= td.x) : (mn <= td.x);
    word |= (uint32_t)b << j;
  }
  Aout[(size_t)npo * WDo + wd] = word;
}

// ---- head: avgpool(4x4) + binary FC (exact in f32) ----
__global__ void __launch_bounds__(64) head_kern(const uint32_t* __restrict__ A6,
                                                const float* __restrict__ fcw,
                                                const float* __restrict__ fcb,
                                                float* __restrict__ fcout) {
  __shared__ uint32_t aw[128];
  __shared__ float feat[256];
  const int n = blockIdx.x, t = threadIdx.x;
  for (int i = t; i < 128; i += 64) aw[i] = A6[(size_t)n * 128 + i];
  __syncthreads();
#pragma unroll
  for (int k = 0; k < 4; k++) {
    const int c = t * 4 + k;
    const int wd = c >> 5, sh = c & 31;
    int cnt = 0;
#pragma unroll
    for (int pos = 0; pos < 16; pos++) cnt += (aw[pos * 8 + wd] >> sh) & 1;
    feat[c] = (float)(cnt - 8) * 0.125f;  // exact
  }
  __syncthreads();
  if (t < 10) {
    float acc = 0.f;  // all partial sums exactly representable
    for (int c = 0; c < 256; c++) acc += (fcw[t * 256 + c] >= 0.f ? feat[c] : -feat[c]);
    fcout[n * 10 + t] = acc + fcb[t];
  }
}

// ---- bn1d over batch: one block, wave per output channel ----
__global__ void __launch_bounds__(640) bn1d_kern(const float* __restrict__ fcout,
                                                 const float* __restrict__ g7,
                                                 const float* __restrict__ be7,
                                                 float* __restrict__ out) {
  const int t = threadIdx.x, o = t >> 6, lane = t & 63;
  double s = 0.0, q = 0.0;
  float v[8];
#pragma unroll
  for (int i = 0; i < 8; i++) {
    v[i] = fcout[(lane + 64 * i) * 10 + o];
    s += v[i];
    q += (double)v[i] * v[i];
  }
#pragma unroll
  for (int off = 32; off; off >>= 1) {
    s += __shfl_down(s, off);
    q += __shfl_down(q, off);
  }
  s = __shfl(s, 0);
  q = __shfl(q, 0);
  const double mu = s / 512.0, var = q / 512.0 - mu * mu;
  const double r = 1.0 / sqrt(var + 1e-5);
  const double al = (double)g7[o] * r;
  const double bt = (double)be7[o] - al * mu;
#pragma unroll
  for (int i = 0; i < 8; i++) out[(lane + 64 * i) * 10 + o] = (float)fma(al, (double)v[i], bt);
}

extern "C" void kernel_launch(void* const* d_in, const int* in_sizes, int n_in,
                              void* d_out, int out_size, void* d_ws, size_t ws_size,
                              hipStream_t stream) {
  const float* x = (const float*)d_in[0];
  const float* w1 = (const float*)d_in[1];
  const float* g1 = (const float*)d_in[3];
  const float* be1 = (const float*)d_in[4];
  const float* w2 = (const float*)d_in[5];
  const float* g2 = (const float*)d_in[7];
  const float* be2 = (const float*)d_in[8];
  const float* w3 = (const float*)d_in[9];
  const float* g3 = (const float*)d_in[11];
  const float* be3 = (const float*)d_in[12];
  const float* w4 = (const float*)d_in[13];
  const float* g4 = (const float*)d_in[15];
  const float* be4 = (const float*)d_in[16];
  const float* w5 = (const float*)d_in[17];
  const float* g5 = (const float*)d_in[19];
  const float* be5 = (const float*)d_in[20];
  const float* w6 = (const float*)d_in[21];
  const float* g6 = (const float*)d_in[23];
  const float* be6 = (const float*)d_in[24];
  const float* fcw = (const float*)d_in[25];
  const float* fcb = (const float*)d_in[26];
  const float* g7 = (const float*)d_in[27];
  const float* be7 = (const float*)d_in[28];
  float* out = (float*)d_out;

  char* ws = (char*)d_ws;
  size_t off = 0;
  auto take = [&](size_t bytes) -> char* {
    char* p = ws + off;
    off = (off + bytes + 255) & ~(size_t)255;
    return p;
  };
  uint32_t* A1 = (uint32_t*)take((size_t)512 * 1024 * 2 * 4);
  uint32_t* A2 = (uint32_t*)take((size_t)512 * 256 * 2 * 4);
  uint32_t* A3 = (uint32_t*)take((size_t)512 * 256 * 4 * 4);
  uint32_t* A4 = (uint32_t*)take((size_t)512 * 64 * 4 * 4);
  uint32_t* A5 = (uint32_t*)take((size_t)512 * 64 * 8 * 4);
  uint32_t* A6 = (uint32_t*)take((size_t)512 * 16 * 8 * 4);
  uint32_t* Wrec = (uint32_t*)take((size_t)46080 * 4);
  double2* part1 = (double2*)take((size_t)64 * 512 * 16);
  unsigned long long* stats = (unsigned long long*)take((size_t)832 * 2 * 8);
  double2* thrD = (double2*)take((size_t)64 * 16);
  double* teD = (double*)take((size_t)64 * 8);
  int2* thri = (int2*)take((size_t)832 * 8);
  float* fcout = (float*)take((size_t)512 * 10 * 4);
  short* raw = (short*)take((size_t)64 * 512 * 1024 * 2);
  int* mm = (int*)raw;  // aliased: mm and raw lifetimes don't overlap
  (void)ws_size; (void)in_sizes; (void)n_in; (void)out_size;

  hipMemsetAsync(stats, 0, 832 * 2 * 8, stream);

  pack_all<<<832, 64, 0, stream>>>(w2, w3, w4, w5, w6, Wrec);

  conv1_p1<<<dim3(512, 2), 256, 0, stream>>>(x, w1, part1);
  conv1_fin<<<1, 64, 0, stream>>>(part1, g1, be1, w1, thrD, teD);
  conv1_p2<<<dim3(512, 2), 256, 0, stream>>>(x, w1, thrD, teD, A1);

  // L2 (pool): 32x32, WD2, CO=64
  bconv_pool<32, 32, 2, 16, 1, 256, 6><<<dim3(512, 4), 256, 0, stream>>>(A1, Wrec + 0, mm, stats + 0);
  bin_fin<<<1, 64, 0, stream>>>(stats + 0, g2, be2, thri + 0, 64, 512.0 * 1024.0);
  binpool_mm<256, 64><<<1024, 256, 0, stream>>>(mm, thri + 0, A2);

  // L3 (no pool): 16x16, WD2, CO=128
  bconv2<16, 16, 2, 16, 2, 2, 256, 6><<<dim3(256, 8), 256, 0, stream>>>(A2, Wrec + 2048, raw, stats + 128);
  bin_fin<<<2, 64, 0, stream>>>(stats + 128, g3, be3, thri + 64, 128, 512.0 * 256.0);
  binz2<256, 128><<<1024, 256, 0, stream>>>(raw, thri + 64, A3);

  // L4 (pool): 16x16, WD4, CO=128
  bconv_pool<16, 16, 4, 8, 4, 256, 4><<<dim3(128, 16), 256, 0, stream>>>(A3, Wrec + 6144, mm, stats + 384);
  bin_fin<<<2, 64, 0, stream>>>(stats + 384, g4, be4, thri + 192, 128, 512.0 * 256.0);
  binpool_mm<64, 128><<<512, 256, 0, stream>>>(mm, thri + 192, A4);

  // L5 (no pool): 8x8, WD4, CO=256
  bconv2<8, 8, 4, 8, 2, 8, 256, 4><<<dim3(64, 32), 256, 0, stream>>>(A4, Wrec + 12288, raw, stats + 640);
  bin_fin<<<4, 64, 0, stream>>>(stats + 640, g5, be5, thri + 320, 256, 512.0 * 64.0);
  binz2<64, 256><<<512, 256, 0, stream>>>(raw, thri + 320, A5);

  // L6 (pool): 8x8, WD8, CO=256 -- lane-split kernel
  bconv6<16, 4, 6><<<dim3(128, 16), 256, 0, stream>>>(A5, Wrec + 24576, mm, stats + 1152);
  bin_fin<<<4, 64, 0, stream>>>(stats + 1152, g6, be6, thri + 576, 256, 512.0 * 64.0);
  binpool_mm<16, 256><<<256, 256, 0, stream>>>(mm, thri + 576, A6);

  head_kern<<<512, 64, 0, stream>>>(A6, fcw, fcb, fcout);
  bn1d_kern<<<1, 640, 0, stream>>>(fcout, g7, be7, out);
}